// Round 4
// baseline (266.647 us; speedup 1.0000x reference)
//
#include <hip/hip_runtime.h>
#include <hip/hip_bf16.h>
#include <stdint.h>

typedef __attribute__((ext_vector_type(8))) short short8;
typedef __attribute__((ext_vector_type(4))) short short4v;
typedef __attribute__((ext_vector_type(4))) float f32x4;

#define MFMA(a, b, c) __builtin_amdgcn_mfma_f32_16x16x32_bf16((a), (b), (c), 0, 0, 0)

#define C1 0.18033688011112042f      // 0.125 * log2(e)
#define INV_C1 5.545177444479562f    // 1 / C1

// packed fp32x2 -> bf16x2 (RNE)
static __device__ __forceinline__ unsigned int f2bf2(float x, float y) {
  union { __hip_bfloat162 h; unsigned int u; } c;
  c.h = __float22bfloat162_rn(make_float2(x, y));
  return c.u;
}

// int-ordered max on non-negative floats; ws poison (negative int) = identity
static __device__ __forceinline__ void atomic_max_f32(float* addr, float v) {
  atomicMax((int*)addr, __float_as_int(v));
}

// async global->LDS DMA, 16B per lane; LDS dest is wave-uniform base + lane*16
static __device__ __forceinline__ void gl_lds16(const void* g, void* l) {
  __builtin_amdgcn_global_load_lds(
      (const __attribute__((address_space(1))) void*)g,
      (__attribute__((address_space(3))) void*)l, 16, 0, 0);
}

// ---------------- one-shot fp32 -> bf16 conversion of X, Wq, Wk, Wv --------
__global__ __launch_bounds__(256) void k_cvt(
    const float* __restrict__ X, const float* __restrict__ Wq,
    const float* __restrict__ Wk, const float* __restrict__ Wv,
    short* __restrict__ Xb, short* __restrict__ Wb) {
  const int y = blockIdx.y;
  const float* src;
  short* dst;
  int n;
  if (y == 0) {
    src = X; dst = Xb; n = 4096 * 1024;
  } else {
    src = (y == 1) ? Wq : (y == 2) ? Wk : Wv;
    dst = Wb + (y - 1) * 1048576;
    n = 1048576;
  }
  const int i = (blockIdx.x * 256 + threadIdx.x) * 8;
  if (i >= n) return;
  const float4 a = *(const float4*)(src + i);
  const float4 b = *(const float4*)(src + i + 4);
  union { unsigned int u[4]; short8 s; } P;
  P.u[0] = f2bf2(a.x, a.y);
  P.u[1] = f2bf2(a.z, a.w);
  P.u[2] = f2bf2(b.x, b.y);
  P.u[3] = f2bf2(b.z, b.w);
  *(short8*)(dst + i) = P.s;
}

// ---------------- QKV projection: Y = X @ W^T + b (bf16 inputs) ------------
// (unchanged from round 3 — isolate attribution; counters next round)
__global__ __launch_bounds__(256) void k_qkv(
    const short* __restrict__ Xb, const short* __restrict__ Wball,
    const float* __restrict__ bq, const float* __restrict__ bk,
    const float* __restrict__ bv,
    short* __restrict__ Qo, short* __restrict__ Ko, short* __restrict__ Vo,
    float* __restrict__ stats) {
  const int fid = (blockIdx.z * 32 + blockIdx.y) * 8 + blockIdx.x;
  const int sid = (fid & 7) * 96 + (fid >> 3);
  const int colb = sid & 7;   // N-tile 0..7
  const int zy = sid >> 3;    // 0..95
  const int z = zy >> 5;      // 0..2 (Q/K/V)
  const int yb = zy & 31;     // M-tile 0..31

  const short* W = Wball + z * 1048576;
  const float* bias = (z == 0) ? bq : (z == 1) ? bk : bv;
  short* out = (z == 0) ? Qo : (z == 1) ? Ko : Vo;
  const bool qk = (z < 2);

  __shared__ __align__(16) short AB[8192];  // As=[0,4096) Bs=[4096,8192), [128][32]
  __shared__ float red[4];

  const int t = threadIdx.x;
  const int lane = t & 63;
  const int w = t >> 6;
  const int l16 = lane & 15, quad = lane >> 4;
  const int wr = (w >> 1) * 64, wc = (w & 1) * 64;
  const int row0 = yb * 128;
  const int col0 = colb * 128;

  const int grow = w * 16 + (lane >> 2);
  const int gcol = (lane & 3) * 8;
  const short* ag = Xb + (size_t)(row0 + grow) * 1024 + gcol;
  const short* bg = W + (size_t)(col0 + grow) * 1024 + gcol;
  short* al = AB + w * 512;         // wave-uniform
  short* bl = AB + 4096 + w * 512;

  const int f0o = qk ? (4096 + wc * 32) : (wr * 32);
  const int f1o = qk ? (wr * 32) : (4096 + wc * 32);

  f32x4 acc[4][4];
#pragma unroll
  for (int i = 0; i < 4; ++i)
#pragma unroll
    for (int j = 0; j < 4; ++j) acc[i][j] = {0.f, 0.f, 0.f, 0.f};

  for (int kk = 0; kk < 32; ++kk) {
    __syncthreads();  // prior iter's LDS reads done
    const int k0 = kk * 32;
#pragma unroll
    for (int c = 0; c < 2; ++c) {  // 2 chunks x 64 rows per matrix
      gl_lds16(ag + c * 65536 + k0, al + c * 2048);
      gl_lds16(bg + c * 65536 + k0, bl + c * 2048);
    }
    __syncthreads();  // vmcnt(0) drain before barrier -> tile published
    short8 fr0[4], fr1[4];
#pragma unroll
    for (int a = 0; a < 4; ++a)
      fr0[a] = *(const short8*)&AB[f0o + (a * 16 + l16) * 32 + quad * 8];
#pragma unroll
    for (int b = 0; b < 4; ++b)
      fr1[b] = *(const short8*)&AB[f1o + (b * 16 + l16) * 32 + quad * 8];
#pragma unroll
    for (int a = 0; a < 4; ++a)
#pragma unroll
      for (int b = 0; b < 4; ++b) acc[a][b] = MFMA(fr0[a], fr1[b], acc[a][b]);
  }

  const float qs = (z == 0) ? C1 : 1.0f;
  float amax = 0.f;
  if (qk) {
#pragma unroll
    for (int a = 0; a < 4; ++a) {
      const int dg = col0 + wc + a * 16 + quad * 4;
      const float4 b4 = *(const float4*)&bias[dg];
      const int h = dg >> 6, dl = dg & 63;
#pragma unroll
      for (int b = 0; b < 4; ++b) {
        const int sg = row0 + wr + b * 16 + l16;
        const float y0 = acc[a][b][0] + b4.x;
        const float y1 = acc[a][b][1] + b4.y;
        const float y2 = acc[a][b][2] + b4.z;
        const float y3 = acc[a][b][3] + b4.w;
        amax = fmaxf(amax, fmaxf(fmaxf(fabsf(y0), fabsf(y1)), fmaxf(fabsf(y2), fabsf(y3))));
        union { unsigned int u[2]; short4v s; } pk;
        pk.u[0] = f2bf2(y0 * qs, y1 * qs);
        pk.u[1] = f2bf2(y2 * qs, y3 * qs);
        const int bidx = sg >> 11, sl = sg & 2047;
        *(short4v*)&out[(size_t)(((bidx << 4) | h) * 2048 + sl) * 64 + dl] = pk.s;
      }
    }
  } else {
#pragma unroll
    for (int a = 0; a < 4; ++a) {
      const int sg = row0 + wr + a * 16 + quad * 4;
      const int bidx = sg >> 11, sl = sg & 2047;
#pragma unroll
      for (int b = 0; b < 4; ++b) {
        const int dg = col0 + wc + b * 16 + l16;
        const float bvf = bias[dg];
        const int h = dg >> 6, dl = dg & 63;
        const float y0 = acc[a][b][0] + bvf;
        const float y1 = acc[a][b][1] + bvf;
        const float y2 = acc[a][b][2] + bvf;
        const float y3 = acc[a][b][3] + bvf;
        amax = fmaxf(amax, fmaxf(fmaxf(fabsf(y0), fabsf(y1)), fmaxf(fabsf(y2), fabsf(y3))));
        union { unsigned int u[2]; short4v s; } pk;
        pk.u[0] = f2bf2(y0, y1);
        pk.u[1] = f2bf2(y2, y3);
        *(short4v*)&out[(size_t)(((bidx << 4) | h) * 64 + dl) * 2048 + sl] = pk.s;
      }
    }
  }
#pragma unroll
  for (int off = 32; off > 0; off >>= 1)
    amax = fmaxf(amax, __shfl_xor(amax, off, 64));
  if (lane == 0) red[w] = amax;
  __syncthreads();
  if (t == 0) {
    float m = fmaxf(fmaxf(red[0], red[1]), fmaxf(red[2], red[3]));
    atomic_max_f32(&stats[z], m);  // 0=q,1=k,2=v
  }
}

// ---------------- flash attention v3: K-frags from GLOBAL (L2), V in LDS --
// grid (32,32) = 1024 blocks; block 256 = 4 waves; wave owns 16 q-rows
// (block q-tile = 64). K A-frags are prefetched global->VGPR one kt ahead
// (32 regs; the frag pattern = 16 rows x 64B aligned segments, L2-served,
// XCD-swizzle keeps each head's K/V L2-resident). Removes K staging + K
// LDS frag reads entirely: LDS/block-kt drops 176->56 KB-equiv per q-row
// basis. V stays LDS-staged (transposed [dh][s] input); Ps per-wave.
// Q arrives pre-scaled by C1 so sacc IS the exp2 argument. No-rescale
// softmax: per-lane running (max x, min x, sum exp2 x); qk_out_max =
// max(m,-xmin)/C1; O accumulated unnormalized, O = O'/l at the end.
// XCD swizzle: 1024 = 8*128 bijective; XCD k owns heads 4k..4k+3.
__global__ __launch_bounds__(256, 4) void k_attn(
    const short* __restrict__ Q, const short* __restrict__ K,
    const short* __restrict__ V, float* __restrict__ O,
    float* __restrict__ stats) {
  const int fid = blockIdx.y * 32 + blockIdx.x;
  const int sid = ((fid & 7) << 7) + (fid >> 3);  // bijective: 1024 = 8*128
  const int bh = sid >> 5;
  const int q0 = (sid & 31) << 6;
  const short* Qh = Q + (size_t)bh * 2048 * 64;
  const short* Kh = K + (size_t)bh * 2048 * 64;
  const short* Vh = V + (size_t)bh * 2048 * 64;  // [dh=64][s=2048]

  __shared__ __align__(16) short Vts[64 * 72];  // [dh][key]
  __shared__ __align__(16) short Ps[4][16 * 72];
  __shared__ float redA[4], redB[4];

  const int t = threadIdx.x, lane = t & 63, w = t >> 6;  // w 0..3
  const int l16 = lane & 15, quad = lane >> 4;
  const int srow = t >> 2, scol = (t & 3) * 16;  // V staging: 2 short8/thread
  short* myPs = &Ps[w][0];

  // Q B-frags (loop-invariant): q-row = q0 + w*16 + l16 (pre-scaled by C1)
  short8 bq0, bq1;
  {
    const short* qsrc = Qh + (q0 + w * 16 + l16) * 64 + quad * 8;
    bq0 = *(const short8*)qsrc;
    bq1 = *(const short8*)(qsrc + 32);
  }

  // K A-frag global base: lane (l16,quad) reads key row (kt*64 + j*16 + l16),
  // bytes [hk*64 + quad*16 .. +15] -> imm offsets j*1024 + hk*32 shorts.
  const short* kg = Kh + l16 * 64 + quad * 8;

  float m_lane = -1e30f, l_lane = 0.f, xmin_lane = 1e30f;
  f32x4 o_acc[4];
#pragma unroll
  for (int jn = 0; jn < 4; ++jn) o_acc[jn] = {0.f, 0.f, 0.f, 0.f};
  const f32x4 zero = {0.f, 0.f, 0.f, 0.f};

  // prologue: prefetch V tile kt=0 (LDS-bound regs) + K frags kt=0 (VGPR)
  short8 pv0 = *(const short8*)(Vh + srow * 2048 + scol);
  short8 pv1 = *(const short8*)(Vh + srow * 2048 + scol + 8);
  short8 kf[4][2];
#pragma unroll
  for (int j = 0; j < 4; ++j)
#pragma unroll
    for (int hk = 0; hk < 2; ++hk)
      kf[j][hk] = *(const short8*)(kg + j * 1024 + hk * 32);

  for (int kt = 0; kt < 32; ++kt) {
    __syncthreads();  // prev-iter Vts reads done
    *(short8*)&Vts[srow * 72 + scol] = pv0;
    *(short8*)&Vts[srow * 72 + scol + 8] = pv1;
    const int ktn = (kt < 31) ? kt + 1 : 31;
    {  // prefetch next V tile; in flight across barrier + compute
      const short* vsrc = Vh + srow * 2048 + ktn * 64 + scol;
      pv0 = *(const short8*)vsrc;
      pv1 = *(const short8*)(vsrc + 8);
    }
    __syncthreads();  // Vts published

    // S^T = K Q^T from register K-frags (loaded last iter from L2)
    f32x4 sacc[4];
#pragma unroll
    for (int j = 0; j < 4; ++j)
      sacc[j] = MFMA(kf[j][1], bq1, MFMA(kf[j][0], bq0, zero));

    // prefetch K frags for kt+1 (WAR on kf is issue-ordered; safe)
    {
      const short* kgn = kg + ktn * 4096;
#pragma unroll
      for (int j = 0; j < 4; ++j)
#pragma unroll
        for (int hk = 0; hk < 2; ++hk)
          kf[j][hk] = *(const short8*)(kgn + j * 1024 + hk * 32);
    }

    // softmax: x already = s*C1; track max/min/sum, exp2, pack to bf16
    {
      float pmax = m_lane, psum = l_lane, xmn = xmin_lane;
#pragma unroll
      for (int j = 0; j < 4; ++j) {
        const float x0 = sacc[j][0], x1 = sacc[j][1];
        const float x2 = sacc[j][2], x3 = sacc[j][3];
        // v_max3 / v_min3-fusable nesting
        pmax = fmaxf(fmaxf(x0, fmaxf(x1, x2)), fmaxf(x3, pmax));
        xmn = fminf(fminf(x0, fminf(x1, x2)), fminf(x3, xmn));
        const float e0 = exp2f(x0), e1 = exp2f(x1);
        const float e2 = exp2f(x2), e3 = exp2f(x3);
        psum += (e0 + e1) + (e2 + e3);
        union { unsigned int u[2]; short4v s; } pk;
        pk.u[0] = f2bf2(e0, e1);
        pk.u[1] = f2bf2(e2, e3);
        *(short4v*)&myPs[l16 * 72 + j * 16 + quad * 4] = pk.s;
      }
      m_lane = pmax;
      l_lane = psum;
      xmin_lane = xmn;
    }
    asm volatile("" ::: "memory");  // same-wave DS pipe in-order

    // O' += P V (unnormalized)
#pragma unroll
    for (int tstep = 0; tstep < 2; ++tstep) {
      short8 ap = *(const short8*)&myPs[l16 * 72 + tstep * 32 + quad * 8];
#pragma unroll
      for (int jn = 0; jn < 4; ++jn) {
        short8 vf = *(const short8*)&Vts[(jn * 16 + l16) * 72 + tstep * 32 + quad * 8];
        o_acc[jn] = MFMA(ap, vf, o_acc[jn]);
      }
    }
    asm volatile("" ::: "memory");  // Ps reads done before next iter's writes
  }

  // cross-quad reductions (row r lives at lanes l16=r, all quads)
  float l = l_lane;
  l += __shfl_xor(l, 16, 64);
  l += __shfl_xor(l, 32, 64);
  float m = m_lane;
  m = fmaxf(m, __shfl_xor(m, 16, 64));
  m = fmaxf(m, __shfl_xor(m, 32, 64));
  float xm = xmin_lane;
  xm = fminf(xm, __shfl_xor(xm, 16, 64));
  xm = fminf(xm, __shfl_xor(xm, 32, 64));
  float aw = exp2f(m) / l;
  float qkx = fmaxf(m, -xm);  // in x-units; /C1 at the very end

  // write O = O'/l (FP32) to [B,S,H*DH]
  const int bidx = bh >> 4, h = bh & 15;
  float linv[4];
#pragma unroll
  for (int r = 0; r < 4; ++r)
    linv[r] = 1.0f / __shfl(l, quad * 4 + r, 16);
#pragma unroll
  for (int jn = 0; jn < 4; ++jn) {
    const int d = jn * 16 + l16;
#pragma unroll
    for (int r = 0; r < 4; ++r) {
      const int s_row = q0 + w * 16 + quad * 4 + r;
      O[((size_t)(bidx * 2048 + s_row) * 1024) + h * 64 + d] =
          o_acc[jn][r] * linv[r];
    }
  }

#pragma unroll
  for (int off = 32; off > 0; off >>= 1) {
    qkx = fmaxf(qkx, __shfl_xor(qkx, off, 64));
    aw = fmaxf(aw, __shfl_xor(aw, off, 64));
  }
  if (lane == 0) {
    redA[w] = qkx;
    redB[w] = aw;
  }
  __syncthreads();
  if (t == 0) {
    float a = fmaxf(fmaxf(redA[0], redA[1]), fmaxf(redA[2], redA[3]));
    float b = fmaxf(fmaxf(redB[0], redB[1]), fmaxf(redB[2], redB[3]));
    atomic_max_f32(&stats[3], a * INV_C1);
    atomic_max_f32(&stats[4], b);
  }
}

// ---------------- finalize 6 scalar outputs (FP32) ----------------
// order: q_max, kT_max, qk_out_max, aw_max, v_max, v_out_max(=aw_max)
__global__ void k_fin(const float* __restrict__ stats, float* __restrict__ out) {
  const int i = threadIdx.x;
  if (i == 0) out[0] = stats[0];
  if (i == 1) out[1] = stats[1];
  if (i == 2) out[2] = stats[3];
  if (i == 3) out[3] = stats[4];
  if (i == 4) out[4] = stats[2];
  if (i == 5) out[5] = stats[4];
}

extern "C" void kernel_launch(void* const* d_in, const int* in_sizes, int n_in,
                              void* d_out, int out_size, void* d_ws, size_t ws_size,
                              hipStream_t stream) {
  const float* X = (const float*)d_in[0];
  const float* Wq = (const float*)d_in[1];
  const float* bq = (const float*)d_in[2];
  const float* Wk = (const float*)d_in[3];
  const float* bk = (const float*)d_in[4];
  const float* Wv = (const float*)d_in[5];
  const float* bv = (const float*)d_in[6];
  float* out = (float*)d_out;

  float* stats = (float*)d_ws;  // 8 floats; poison = atomicMax identity
  short* base = (short*)((char*)d_ws + 4096);
  short* Qb = base;                  // 4096*1024
  short* Kb = base + 4194304;        // 4096*1024
  short* Vb = base + 8388608;        // 4096*1024
  short* Xb = base + 12582912;       // 4096*1024
  short* Wb = base + 16777216;       // 3 * 1024*1024

  k_cvt<<<dim3(2048, 4), 256, 0, stream>>>(X, Wq, Wk, Wv, Xb, Wb);
  k_qkv<<<dim3(8, 32, 3), 256, 0, stream>>>(Xb, Wb, bq, bk, bv, Qb, Kb, Vb, stats);
  k_attn<<<dim3(32, 32), 256, 0, stream>>>(Qb, Kb, Vb, out, stats);
  k_fin<<<1, 64, 0, stream>>>(stats, out + 4194304);
}

// Round 5
// 223.389 us; speedup vs baseline: 1.1936x; 1.1936x over previous
//
#include <hip/hip_runtime.h>
#include <hip/hip_bf16.h>
#include <stdint.h>

typedef __attribute__((ext_vector_type(8))) short short8;
typedef __attribute__((ext_vector_type(4))) short short4v;
typedef __attribute__((ext_vector_type(4))) float f32x4;

#define MFMA(a, b, c) __builtin_amdgcn_mfma_f32_16x16x32_bf16((a), (b), (c), 0, 0, 0)

#define C1 0.18033688011112042f      // 0.125 * log2(e)
#define INV_C1 5.545177444479562f    // 1 / C1

// packed fp32x2 -> bf16x2 (RNE)
static __device__ __forceinline__ unsigned int f2bf2(float x, float y) {
  union { __hip_bfloat162 h; unsigned int u; } c;
  c.h = __float22bfloat162_rn(make_float2(x, y));
  return c.u;
}

// int-ordered max on non-negative floats; ws poison (negative int) = identity
static __device__ __forceinline__ void atomic_max_f32(float* addr, float v) {
  atomicMax((int*)addr, __float_as_int(v));
}

// async global->LDS DMA, 16B per lane; LDS dest is wave-uniform base + lane*16
static __device__ __forceinline__ void gl_lds16(const void* g, void* l) {
  __builtin_amdgcn_global_load_lds(
      (const __attribute__((address_space(1))) void*)g,
      (__attribute__((address_space(3))) void*)l, 16, 0, 0);
}

// ---------------- one-shot fp32 -> bf16 conversion of X, Wq, Wk, Wv --------
__global__ __launch_bounds__(256) void k_cvt(
    const float* __restrict__ X, const float* __restrict__ Wq,
    const float* __restrict__ Wk, const float* __restrict__ Wv,
    short* __restrict__ Xb, short* __restrict__ Wb) {
  const int y = blockIdx.y;
  const float* src;
  short* dst;
  int n;
  if (y == 0) {
    src = X; dst = Xb; n = 4096 * 1024;
  } else {
    src = (y == 1) ? Wq : (y == 2) ? Wk : Wv;
    dst = Wb + (y - 1) * 1048576;
    n = 1048576;
  }
  const int i = (blockIdx.x * 256 + threadIdx.x) * 8;
  if (i >= n) return;
  const float4 a = *(const float4*)(src + i);
  const float4 b = *(const float4*)(src + i + 4);
  union { unsigned int u[4]; short8 s; } P;
  P.u[0] = f2bf2(a.x, a.y);
  P.u[1] = f2bf2(a.z, a.w);
  P.u[2] = f2bf2(b.x, b.y);
  P.u[3] = f2bf2(b.z, b.w);
  *(short8*)(dst + i) = P.s;
}

// ---------------- QKV projection: Y = X @ W^T + b (bf16 inputs) ------------
// CHUNK-MAJOR LDS tiles: [4 k-chunk][128 row][16B]. The DMA dest is linear
// (wave-uniform + lane*16, required); the k-chunk interleave is achieved by
// permuting the per-lane GLOBAL source address (m173 pattern). Frag read:
// chunk=quad, byte=row*16 -> bank = 4*row mod 32: each lane-octet sweeps all
// 32 banks exactly once -> conflict-free ds_read_b128 (was ~4-way at [128][32]).
// DMA call (w,c): p=c*4+w covers chunk p>>1, rows (p&1)*64+lane.
// Q/K: acc=MFMA(W,X) -> packed [bh][s][dh] stores; V: acc=MFMA(X,W) ->
// packed [bh][dh][s] stores. Q pre-scaled by C1. XCD-chunked swizzle 768=8*96.
__global__ __launch_bounds__(256) void k_qkv(
    const short* __restrict__ Xb, const short* __restrict__ Wball,
    const float* __restrict__ bq, const float* __restrict__ bk,
    const float* __restrict__ bv,
    short* __restrict__ Qo, short* __restrict__ Ko, short* __restrict__ Vo,
    float* __restrict__ stats) {
  const int fid = (blockIdx.z * 32 + blockIdx.y) * 8 + blockIdx.x;
  const int sid = (fid & 7) * 96 + (fid >> 3);
  const int colb = sid & 7;   // N-tile 0..7
  const int zy = sid >> 3;    // 0..95
  const int z = zy >> 5;      // 0..2 (Q/K/V)
  const int yb = zy & 31;     // M-tile 0..31

  const short* W = Wball + z * 1048576;
  const float* bias = (z == 0) ? bq : (z == 1) ? bk : bv;
  short* out = (z == 0) ? Qo : (z == 1) ? Ko : Vo;
  const bool qk = (z < 2);

  __shared__ __align__(16) short AB[8192];  // A=[0,4096) B=[4096,8192) chunk-major
  __shared__ float red[4];

  const int t = threadIdx.x;
  const int lane = t & 63;
  const int w = t >> 6;
  const int l16 = lane & 15, quad = lane >> 4;
  const int wr = (w >> 1) * 64, wc = (w & 1) * 64;
  const int row0 = yb * 128;
  const int col0 = colb * 128;

  // DMA: wave w handles p=w (c=0) and p=4+w (c=1); row = (w&1)*64 + lane,
  // global k-offset = (p>>1)*8 = (w>>1)*8 + c*16 shorts.
  const short* ag = Xb + (size_t)(row0 + (w & 1) * 64 + lane) * 1024 + (w >> 1) * 8;
  const short* bg = W + (size_t)(col0 + (w & 1) * 64 + lane) * 1024 + (w >> 1) * 8;
  short* al0 = AB + w * 512;
  short* al1 = AB + (4 + w) * 512;
  short* bl0 = AB + 4096 + w * 512;
  short* bl1 = AB + 4096 + (4 + w) * 512;

  // frag bases (z-dependent operand swap): {matbase, rowbase}
  const int f0b = qk ? 4096 : 0, f0r = qk ? wc : wr;
  const int f1b = qk ? 0 : 4096, f1r = qk ? wr : wc;
  const int cq = quad * 1024;  // chunk offset in shorts

  f32x4 acc[4][4];
#pragma unroll
  for (int i = 0; i < 4; ++i)
#pragma unroll
    for (int j = 0; j < 4; ++j) acc[i][j] = {0.f, 0.f, 0.f, 0.f};

  for (int kk = 0; kk < 32; ++kk) {
    __syncthreads();  // prior iter's LDS reads done
    const int k0 = kk * 32;
    gl_lds16(ag + k0, al0);
    gl_lds16(ag + k0 + 16, al1);
    gl_lds16(bg + k0, bl0);
    gl_lds16(bg + k0 + 16, bl1);
    __syncthreads();  // vmcnt(0) drain before barrier -> tile published
    short8 fr0[4], fr1[4];
#pragma unroll
    for (int a = 0; a < 4; ++a)
      fr0[a] = *(const short8*)&AB[f0b + cq + (f0r + a * 16 + l16) * 8];
#pragma unroll
    for (int b = 0; b < 4; ++b)
      fr1[b] = *(const short8*)&AB[f1b + cq + (f1r + b * 16 + l16) * 8];
#pragma unroll
    for (int a = 0; a < 4; ++a)
#pragma unroll
      for (int b = 0; b < 4; ++b) acc[a][b] = MFMA(fr0[a], fr1[b], acc[a][b]);
  }

  const float qs = (z == 0) ? C1 : 1.0f;
  float amax = 0.f;
  if (qk) {
    // acc[a=d-tile][b=s-tile]; C/D: row(quad*4+r)=d, col(l16)=s
#pragma unroll
    for (int a = 0; a < 4; ++a) {
      const int dg = col0 + wc + a * 16 + quad * 4;
      const float4 b4 = *(const float4*)&bias[dg];
      const int h = dg >> 6, dl = dg & 63;
#pragma unroll
      for (int b = 0; b < 4; ++b) {
        const int sg = row0 + wr + b * 16 + l16;
        const float y0 = acc[a][b][0] + b4.x;
        const float y1 = acc[a][b][1] + b4.y;
        const float y2 = acc[a][b][2] + b4.z;
        const float y3 = acc[a][b][3] + b4.w;
        amax = fmaxf(amax, fmaxf(fmaxf(fabsf(y0), fabsf(y1)), fmaxf(fabsf(y2), fabsf(y3))));
        union { unsigned int u[2]; short4v s; } pk;
        pk.u[0] = f2bf2(y0 * qs, y1 * qs);
        pk.u[1] = f2bf2(y2 * qs, y3 * qs);
        const int bidx = sg >> 11, sl = sg & 2047;
        *(short4v*)&out[(size_t)(((bidx << 4) | h) * 2048 + sl) * 64 + dl] = pk.s;
      }
    }
  } else {
    // acc[a=s-tile][b=d-tile]; C/D: row(quad*4+r)=s, col(l16)=d
#pragma unroll
    for (int a = 0; a < 4; ++a) {
      const int sg = row0 + wr + a * 16 + quad * 4;
      const int bidx = sg >> 11, sl = sg & 2047;
#pragma unroll
      for (int b = 0; b < 4; ++b) {
        const int dg = col0 + wc + b * 16 + l16;
        const float bvf = bias[dg];
        const int h = dg >> 6, dl = dg & 63;
        const float y0 = acc[a][b][0] + bvf;
        const float y1 = acc[a][b][1] + bvf;
        const float y2 = acc[a][b][2] + bvf;
        const float y3 = acc[a][b][3] + bvf;
        amax = fmaxf(amax, fmaxf(fmaxf(fabsf(y0), fabsf(y1)), fmaxf(fabsf(y2), fabsf(y3))));
        union { unsigned int u[2]; short4v s; } pk;
        pk.u[0] = f2bf2(y0, y1);
        pk.u[1] = f2bf2(y2, y3);
        *(short4v*)&out[(size_t)(((bidx << 4) | h) * 64 + dl) * 2048 + sl] = pk.s;
      }
    }
  }
#pragma unroll
  for (int off = 32; off > 0; off >>= 1)
    amax = fmaxf(amax, __shfl_xor(amax, off, 64));
  if (lane == 0) red[w] = amax;
  __syncthreads();
  if (t == 0) {
    float m = fmaxf(fmaxf(red[0], red[1]), fmaxf(red[2], red[3]));
    atomic_max_f32(&stats[z], m);  // 0=q,1=k,2=v
  }
}

// ---------------- flash attention: 8 waves x 16 q-rows + T2 XOR swizzle ----
// Round-3 structure (proven 82us) + bank-conflict elimination: Ks/Vts/Ps at
// stride 64 shorts (128B) with 16B-slot XOR swizzle slot^=(row&7) applied on
// BOTH write and read (involution). Frag reads then sweep all 32 banks per
// lane-octet -> conflict-free (was ~4-way at stride-72; 11.5M conflicts).
// grid (16,32)=512 blocks; block 512 = 8 waves; wave owns 16 q-rows.
// Q pre-scaled by C1 -> sacc IS the exp2 arg; no-rescale softmax with
// per-lane (max,min,sum); qk_out_max = max(m,-xmin)/C1; O = O'/l at end.
// XCD swizzle 512 = 8*64: XCD k owns heads 4k..4k+3 (K/V L2-resident).
__global__ __launch_bounds__(512) void k_attn(
    const short* __restrict__ Q, const short* __restrict__ K,
    const short* __restrict__ V, float* __restrict__ O,
    float* __restrict__ stats) {
  const int fid = blockIdx.y * 16 + blockIdx.x;
  const int sid = ((fid & 7) << 6) + (fid >> 3);  // bijective: 512 = 8*64
  const int bh = sid >> 4;
  const int q0 = (sid & 15) << 7;
  const short* Qh = Q + (size_t)bh * 2048 * 64;
  const short* Kh = K + (size_t)bh * 2048 * 64;
  const short* Vh = V + (size_t)bh * 2048 * 64;  // [dh=64][s=2048]

  __shared__ __align__(16) short Ks[64 * 64];   // [key][dh] swizzled
  __shared__ __align__(16) short Vts[64 * 64];  // [dh][key] swizzled
  __shared__ __align__(16) short Ps[8][16 * 64];  // swizzled
  __shared__ float redA[8], redB[8];

  const int t = threadIdx.x, lane = t & 63, w = t >> 6;  // w 0..7
  const int l16 = lane & 15, quad = lane >> 4;
  const int srow = t >> 3;            // staging row 0..63
  const int sslot = t & 7;            // global 16B slot 0..7
  const int wslot = (sslot ^ (srow & 7)) * 8;  // swizzled LDS slot (shorts)
  const int rsw = (l16 & 7);          // read-side row parity bits
  short* myPs = &Ps[w][0];

  // Q B-frags (loop-invariant): q-row = q0 + w*16 + l16 (pre-scaled by C1)
  short8 bq0, bq1;
  {
    const short* qsrc = Qh + (q0 + w * 16 + l16) * 64 + quad * 8;
    bq0 = *(const short8*)qsrc;
    bq1 = *(const short8*)(qsrc + 32);
  }

  float m_lane = -1e30f, l_lane = 0.f, xmin_lane = 1e30f;
  f32x4 o_acc[4];
#pragma unroll
  for (int jn = 0; jn < 4; ++jn) o_acc[jn] = {0.f, 0.f, 0.f, 0.f};
  const f32x4 zero = {0.f, 0.f, 0.f, 0.f};

  // swizzled read slot offsets (shorts): kf0 slot = quad^rsw, kf1 = that^4
  const int ksl0 = (quad ^ rsw) * 8;
  const int ksl1 = ((quad ^ rsw) ^ 4) * 8;

  // prefetch tile kt=0 (coalesced; slot = t&7 of the 64-key/64-dh tile)
  short8 pk0 = *(const short8*)(Kh + srow * 64 + sslot * 8);
  short8 pv0 = *(const short8*)(Vh + srow * 2048 + sslot * 8);

  for (int kt = 0; kt < 32; ++kt) {
    __syncthreads();  // prev-iter LDS reads done
    *(short8*)&Ks[srow * 64 + wslot] = pk0;
    *(short8*)&Vts[srow * 64 + wslot] = pv0;
    {  // prefetch next tile; in flight across barrier + compute
      const int ktn = (kt < 31) ? kt + 1 : 31;
      pk0 = *(const short8*)(Kh + (ktn * 64 + srow) * 64 + sslot * 8);
      pv0 = *(const short8*)(Vh + srow * 2048 + ktn * 64 + sslot * 8);
    }
    __syncthreads();  // tiles published

    // S^T = K Q^T: lane holds 16 keys (j*16+quad*4+r) of q-row l16
    f32x4 sacc[4];
#pragma unroll
    for (int j = 0; j < 4; ++j) {
      const int kb = (j * 16 + l16) * 64;
      short8 kf0 = *(const short8*)&Ks[kb + ksl0];
      short8 kf1 = *(const short8*)&Ks[kb + ksl1];
      sacc[j] = MFMA(kf1, bq1, MFMA(kf0, bq0, zero));
    }

    // softmax: x already = s*C1; track max/min/sum, exp2, pack to bf16
    {
      float pmax = m_lane, psum = l_lane, xmn = xmin_lane;
#pragma unroll
      for (int j = 0; j < 4; ++j) {
        const float x0 = sacc[j][0], x1 = sacc[j][1];
        const float x2 = sacc[j][2], x3 = sacc[j][3];
        pmax = fmaxf(fmaxf(x0, fmaxf(x1, x2)), fmaxf(x3, pmax));
        xmn = fminf(fminf(x0, fminf(x1, x2)), fminf(x3, xmn));
        const float e0 = exp2f(x0), e1 = exp2f(x1);
        const float e2 = exp2f(x2), e3 = exp2f(x3);
        psum += (e0 + e1) + (e2 + e3);
        union { unsigned int u[2]; short4v s; } pk;
        pk.u[0] = f2bf2(e0, e1);
        pk.u[1] = f2bf2(e2, e3);
        // swizzled write: key-range (16j+4q..+3) at row l16
        *(short4v*)&myPs[l16 * 64 + ((j * 16 + quad * 4) ^ (rsw << 3))] = pk.s;
      }
      m_lane = pmax;
      l_lane = psum;
      xmin_lane = xmn;
    }
    asm volatile("" ::: "memory");  // same-wave DS pipe in-order

    // O' += P V (unnormalized); swizzled 16B-slot reads
#pragma unroll
    for (int tstep = 0; tstep < 2; ++tstep) {
      const int psl = (tstep * 32 + quad * 8) ^ (rsw << 3);
      short8 ap = *(const short8*)&myPs[l16 * 64 + psl];
#pragma unroll
      for (int jn = 0; jn < 4; ++jn) {
        short8 vf = *(const short8*)&Vts[(jn * 16 + l16) * 64 + psl];
        o_acc[jn] = MFMA(ap, vf, o_acc[jn]);
      }
    }
    asm volatile("" ::: "memory");  // Ps reads done before next iter's writes
  }

  // cross-quad reductions (row r lives at lanes l16=r, all quads)
  float l = l_lane;
  l += __shfl_xor(l, 16, 64);
  l += __shfl_xor(l, 32, 64);
  float m = m_lane;
  m = fmaxf(m, __shfl_xor(m, 16, 64));
  m = fmaxf(m, __shfl_xor(m, 32, 64));
  float xm = xmin_lane;
  xm = fminf(xm, __shfl_xor(xm, 16, 64));
  xm = fminf(xm, __shfl_xor(xm, 32, 64));
  float aw = exp2f(m) / l;
  float qkx = fmaxf(m, -xm);  // in x-units; /C1 at the very end

  // write O = O'/l (FP32) to [B,S,H*DH]
  const int bidx = bh >> 4, h = bh & 15;
  float linv[4];
#pragma unroll
  for (int r = 0; r < 4; ++r)
    linv[r] = 1.0f / __shfl(l, quad * 4 + r, 16);
#pragma unroll
  for (int jn = 0; jn < 4; ++jn) {
    const int d = jn * 16 + l16;
#pragma unroll
    for (int r = 0; r < 4; ++r) {
      const int s_row = q0 + w * 16 + quad * 4 + r;
      O[((size_t)(bidx * 2048 + s_row) * 1024) + h * 64 + d] =
          o_acc[jn][r] * linv[r];
    }
  }

#pragma unroll
  for (int off = 32; off > 0; off >>= 1) {
    qkx = fmaxf(qkx, __shfl_xor(qkx, off, 64));
    aw = fmaxf(aw, __shfl_xor(aw, off, 64));
  }
  if (lane == 0) {
    redA[w] = qkx;
    redB[w] = aw;
  }
  __syncthreads();
  if (t == 0) {
    float a = redA[0], b = redB[0];
#pragma unroll
    for (int i = 1; i < 8; ++i) {
      a = fmaxf(a, redA[i]);
      b = fmaxf(b, redB[i]);
    }
    atomic_max_f32(&stats[3], a * INV_C1);
    atomic_max_f32(&stats[4], b);
  }
}

// ---------------- finalize 6 scalar outputs (FP32) ----------------
// order: q_max, kT_max, qk_out_max, aw_max, v_max, v_out_max(=aw_max)
__global__ void k_fin(const float* __restrict__ stats, float* __restrict__ out) {
  const int i = threadIdx.x;
  if (i == 0) out[0] = stats[0];
  if (i == 1) out[1] = stats[1];
  if (i == 2) out[2] = stats[3];
  if (i == 3) out[3] = stats[4];
  if (i == 4) out[4] = stats[2];
  if (i == 5) out[5] = stats[4];
}

extern "C" void kernel_launch(void* const* d_in, const int* in_sizes, int n_in,
                              void* d_out, int out_size, void* d_ws, size_t ws_size,
                              hipStream_t stream) {
  const float* X = (const float*)d_in[0];
  const float* Wq = (const float*)d_in[1];
  const float* bq = (const float*)d_in[2];
  const float* Wk = (const float*)d_in[3];
  const float* bk = (const float*)d_in[4];
  const float* Wv = (const float*)d_in[5];
  const float* bv = (const float*)d_in[6];
  float* out = (float*)d_out;

  float* stats = (float*)d_ws;  // 8 floats; poison = atomicMax identity
  short* base = (short*)((char*)d_ws + 4096);
  short* Qb = base;                  // 4096*1024
  short* Kb = base + 4194304;        // 4096*1024
  short* Vb = base + 8388608;        // 4096*1024
  short* Xb = base + 12582912;       // 4096*1024
  short* Wb = base + 16777216;       // 3 * 1024*1024

  k_cvt<<<dim3(2048, 4), 256, 0, stream>>>(X, Wq, Wk, Wv, Xb, Wb);
  k_qkv<<<dim3(8, 32, 3), 256, 0, stream>>>(Xb, Wb, bq, bk, bv, Qb, Kb, Vb, stats);
  k_attn<<<dim3(16, 32), 512, 0, stream>>>(Qb, Kb, Vb, out, stats);
  k_fin<<<1, 64, 0, stream>>>(stats, out + 4194304);
}

// Round 6
// 204.463 us; speedup vs baseline: 1.3041x; 1.0926x over previous
//
#include <hip/hip_runtime.h>
#include <hip/hip_bf16.h>
#include <stdint.h>

typedef __attribute__((ext_vector_type(8))) short short8;
typedef __attribute__((ext_vector_type(4))) short short4v;
typedef __attribute__((ext_vector_type(4))) float f32x4;

#define MFMA(a, b, c) __builtin_amdgcn_mfma_f32_16x16x32_bf16((a), (b), (c), 0, 0, 0)

#define C1 0.18033688011112042f      // 0.125 * log2(e)
#define INV_C1 5.545177444479562f    // 1 / C1

// packed fp32x2 -> bf16x2 (RNE)
static __device__ __forceinline__ unsigned int f2bf2(float x, float y) {
  union { __hip_bfloat162 h; unsigned int u; } c;
  c.h = __float22bfloat162_rn(make_float2(x, y));
  return c.u;
}

// single-instruction HW paths (libm/header versions expand to 6-11 instrs)
static __device__ __forceinline__ float exp2_fast(float x) {
  float r;
  asm("v_exp_f32 %0, %1" : "=v"(r) : "v"(x));
  return r;
}
static __device__ __forceinline__ unsigned int cvtpk(float lo, float hi) {
  unsigned int r;  // dst.lo = bf16(lo), dst.hi = bf16(hi), RNE
  asm("v_cvt_pk_bf16_f32 %0, %1, %2" : "=v"(r) : "v"(lo), "v"(hi));
  return r;
}

// int-ordered max on non-negative floats; ws poison (negative int) = identity
static __device__ __forceinline__ void atomic_max_f32(float* addr, float v) {
  atomicMax((int*)addr, __float_as_int(v));
}

// async global->LDS DMA, 16B per lane; LDS dest is wave-uniform base + lane*16
static __device__ __forceinline__ void gl_lds16(const void* g, void* l) {
  __builtin_amdgcn_global_load_lds(
      (const __attribute__((address_space(1))) void*)g,
      (__attribute__((address_space(3))) void*)l, 16, 0, 0);
}

// ---------------- one-shot fp32 -> bf16 conversion of X, Wq, Wk, Wv --------
__global__ __launch_bounds__(256) void k_cvt(
    const float* __restrict__ X, const float* __restrict__ Wq,
    const float* __restrict__ Wk, const float* __restrict__ Wv,
    short* __restrict__ Xb, short* __restrict__ Wb) {
  const int y = blockIdx.y;
  const float* src;
  short* dst;
  int n;
  if (y == 0) {
    src = X; dst = Xb; n = 4096 * 1024;
  } else {
    src = (y == 1) ? Wq : (y == 2) ? Wk : Wv;
    dst = Wb + (y - 1) * 1048576;
    n = 1048576;
  }
  const int i = (blockIdx.x * 256 + threadIdx.x) * 8;
  if (i >= n) return;
  const float4 a = *(const float4*)(src + i);
  const float4 b = *(const float4*)(src + i + 4);
  union { unsigned int u[4]; short8 s; } P;
  P.u[0] = f2bf2(a.x, a.y);
  P.u[1] = f2bf2(a.z, a.w);
  P.u[2] = f2bf2(b.x, b.y);
  P.u[3] = f2bf2(b.z, b.w);
  *(short8*)(dst + i) = P.s;
}

// ---------------- QKV projection: Y = X @ W^T + b (bf16 inputs) ------------
// 2-PHASE DOUBLE-BUFFER (T3 minimum): stage next k-tile right after the
// barrier, compute current tile under the in-flight loads, ONE barrier per
// k-step. The barrier's implicit vmcnt(0) drains loads issued a full
// compute-phase earlier -> L2/HBM latency hidden (was fully exposed by the
// stage->barrier->compute 2-barrier structure; measured all-pipes-idle).
// Distinct named LDS arrays A0/A1 keep alias analysis from inserting a
// spurious vmcnt wait between stage and ds_read.
// CHUNK-MAJOR tiles [4 k-chunk][128 row][16B]: frag read bank = 4*row mod 32
// -> conflict-free (measured 0 conflicts round 5). DMA dest linear; chunk
// interleave via per-lane GLOBAL source address (m173 pattern).
// Q/K: acc=MFMA(W,X) -> packed [bh][s][dh] stores; V: acc=MFMA(X,W) ->
// packed [bh][dh][s] stores. Q pre-scaled by C1. XCD-chunked swizzle 768=8*96.
__global__ __launch_bounds__(256) void k_qkv(
    const short* __restrict__ Xb, const short* __restrict__ Wball,
    const float* __restrict__ bq, const float* __restrict__ bk,
    const float* __restrict__ bv,
    short* __restrict__ Qo, short* __restrict__ Ko, short* __restrict__ Vo,
    float* __restrict__ stats) {
  const int fid = (blockIdx.z * 32 + blockIdx.y) * 8 + blockIdx.x;
  const int sid = (fid & 7) * 96 + (fid >> 3);
  const int colb = sid & 7;   // N-tile 0..7
  const int zy = sid >> 3;    // 0..95
  const int z = zy >> 5;      // 0..2 (Q/K/V)
  const int yb = zy & 31;     // M-tile 0..31

  const short* W = Wball + z * 1048576;
  const float* bias = (z == 0) ? bq : (z == 1) ? bk : bv;
  short* out = (z == 0) ? Qo : (z == 1) ? Ko : Vo;
  const bool qk = (z < 2);

  __shared__ __align__(16) short A0[8192];  // A=[0,4096) B=[4096,8192) chunk-major
  __shared__ __align__(16) short A1[8192];
  __shared__ float red[4];

  const int t = threadIdx.x;
  const int lane = t & 63;
  const int w = t >> 6;
  const int l16 = lane & 15, quad = lane >> 4;
  const int wr = (w >> 1) * 64, wc = (w & 1) * 64;
  const int row0 = yb * 128;
  const int col0 = colb * 128;

  // DMA: wave w covers chunk-pairs p=w and p=4+w; row=(w&1)*64+lane,
  // global k-offset = (w>>1)*8 + c*16 shorts; LDS shorts [p*512,+512).
  const short* ag = Xb + (size_t)(row0 + (w & 1) * 64 + lane) * 1024 + (w >> 1) * 8;
  const short* bg = W + (size_t)(col0 + (w & 1) * 64 + lane) * 1024 + (w >> 1) * 8;

  // frag bases (z-dependent operand swap): {matbase, rowbase}
  const int f0b = qk ? 4096 : 0, f0r = qk ? wc : wr;
  const int f1b = qk ? 0 : 4096, f1r = qk ? wr : wc;
  const int cq = quad * 1024;  // chunk offset in shorts

  f32x4 acc[4][4];
#pragma unroll
  for (int i = 0; i < 4; ++i)
#pragma unroll
    for (int j = 0; j < 4; ++j) acc[i][j] = {0.f, 0.f, 0.f, 0.f};

#define STAGE(buf, kk1)                                  \
  do {                                                   \
    const int k0_ = (kk1) * 32;                          \
    gl_lds16(ag + k0_, (buf) + w * 512);                 \
    gl_lds16(ag + k0_ + 16, (buf) + (4 + w) * 512);      \
    gl_lds16(bg + k0_, (buf) + 4096 + w * 512);          \
    gl_lds16(bg + k0_ + 16, (buf) + 4096 + (4 + w) * 512); \
  } while (0)

#define COMPUTE(buf)                                                   \
  do {                                                                 \
    short8 fr0[4], fr1[4];                                             \
    _Pragma("unroll") for (int a = 0; a < 4; ++a)                      \
        fr0[a] = *(const short8*)&(buf)[f0b + cq + (f0r + a * 16 + l16) * 8]; \
    _Pragma("unroll") for (int b = 0; b < 4; ++b)                      \
        fr1[b] = *(const short8*)&(buf)[f1b + cq + (f1r + b * 16 + l16) * 8]; \
    _Pragma("unroll") for (int a = 0; a < 4; ++a)                      \
        _Pragma("unroll") for (int b = 0; b < 4; ++b)                  \
            acc[a][b] = MFMA(fr0[a], fr1[b], acc[a][b]);               \
  } while (0)

  STAGE(A0, 0);
  for (int kk2 = 0; kk2 < 16; ++kk2) {
    __syncthreads();  // drains vmcnt(0): A0 loads (issued a phase ago) done
    STAGE(A1, 2 * kk2 + 1);
    COMPUTE(A0);
    __syncthreads();  // A1 loads done; A0 reads done -> safe to overwrite
    if (kk2 < 15) STAGE(A0, 2 * kk2 + 2);
    COMPUTE(A1);
  }
#undef STAGE
#undef COMPUTE

  const float qs = (z == 0) ? C1 : 1.0f;
  float amax = 0.f;
  if (qk) {
    // acc[a=d-tile][b=s-tile]; C/D: row(quad*4+r)=d, col(l16)=s
#pragma unroll
    for (int a = 0; a < 4; ++a) {
      const int dg = col0 + wc + a * 16 + quad * 4;
      const float4 b4 = *(const float4*)&bias[dg];
      const int h = dg >> 6, dl = dg & 63;
#pragma unroll
      for (int b = 0; b < 4; ++b) {
        const int sg = row0 + wr + b * 16 + l16;
        const float y0 = acc[a][b][0] + b4.x;
        const float y1 = acc[a][b][1] + b4.y;
        const float y2 = acc[a][b][2] + b4.z;
        const float y3 = acc[a][b][3] + b4.w;
        amax = fmaxf(amax, fmaxf(fmaxf(fabsf(y0), fabsf(y1)), fmaxf(fabsf(y2), fabsf(y3))));
        union { unsigned int u[2]; short4v s; } pk;
        pk.u[0] = cvtpk(y0 * qs, y1 * qs);
        pk.u[1] = cvtpk(y2 * qs, y3 * qs);
        const int bidx = sg >> 11, sl = sg & 2047;
        *(short4v*)&out[(size_t)(((bidx << 4) | h) * 2048 + sl) * 64 + dl] = pk.s;
      }
    }
  } else {
    // acc[a=s-tile][b=d-tile]; C/D: row(quad*4+r)=s, col(l16)=d
#pragma unroll
    for (int a = 0; a < 4; ++a) {
      const int sg = row0 + wr + a * 16 + quad * 4;
      const int bidx = sg >> 11, sl = sg & 2047;
#pragma unroll
      for (int b = 0; b < 4; ++b) {
        const int dg = col0 + wc + b * 16 + l16;
        const float bvf = bias[dg];
        const int h = dg >> 6, dl = dg & 63;
        const float y0 = acc[a][b][0] + bvf;
        const float y1 = acc[a][b][1] + bvf;
        const float y2 = acc[a][b][2] + bvf;
        const float y3 = acc[a][b][3] + bvf;
        amax = fmaxf(amax, fmaxf(fmaxf(fabsf(y0), fabsf(y1)), fmaxf(fabsf(y2), fabsf(y3))));
        union { unsigned int u[2]; short4v s; } pk;
        pk.u[0] = cvtpk(y0, y1);
        pk.u[1] = cvtpk(y2, y3);
        *(short4v*)&out[(size_t)(((bidx << 4) | h) * 64 + dl) * 2048 + sl] = pk.s;
      }
    }
  }
#pragma unroll
  for (int off = 32; off > 0; off >>= 1)
    amax = fmaxf(amax, __shfl_xor(amax, off, 64));
  if (lane == 0) red[w] = amax;
  __syncthreads();
  if (t == 0) {
    float m = fmaxf(fmaxf(red[0], red[1]), fmaxf(red[2], red[3]));
    atomic_max_f32(&stats[z], m);  // 0=q,1=k,2=v
  }
}

// ---------------- flash attention: 8 waves x 16 q-rows + T2 XOR swizzle ----
// Round-5 structure (conflicts 2.1M, but VALU-bound at 55%). This round:
// replace libm exp2f (~6-8 instr __ocml expansion) with raw v_exp_f32 and
// the __float22bfloat162_rn integer-RNE dance (~11 instr/pair) with
// v_cvt_pk_bf16_f32 -- cuts softmax VALU instrs ~2x. Structure unchanged.
// grid (16,32)=512 blocks; block 512 = 8 waves; wave owns 16 q-rows.
// Q pre-scaled by C1 -> sacc IS the exp2 arg; no-rescale softmax with
// per-lane (max,min,sum); qk_out_max = max(m,-xmin)/C1; O = O'/l at end.
// XCD swizzle 512 = 8*64: XCD k owns heads 4k..4k+3 (K/V L2-resident).
__global__ __launch_bounds__(512) void k_attn(
    const short* __restrict__ Q, const short* __restrict__ K,
    const short* __restrict__ V, float* __restrict__ O,
    float* __restrict__ stats) {
  const int fid = blockIdx.y * 16 + blockIdx.x;
  const int sid = ((fid & 7) << 6) + (fid >> 3);  // bijective: 512 = 8*64
  const int bh = sid >> 4;
  const int q0 = (sid & 15) << 7;
  const short* Qh = Q + (size_t)bh * 2048 * 64;
  const short* Kh = K + (size_t)bh * 2048 * 64;
  const short* Vh = V + (size_t)bh * 2048 * 64;  // [dh=64][s=2048]

  __shared__ __align__(16) short Ks[64 * 64];   // [key][dh] swizzled
  __shared__ __align__(16) short Vts[64 * 64];  // [dh][key] swizzled
  __shared__ __align__(16) short Ps[8][16 * 64];  // swizzled
  __shared__ float redA[8], redB[8];

  const int t = threadIdx.x, lane = t & 63, w = t >> 6;  // w 0..7
  const int l16 = lane & 15, quad = lane >> 4;
  const int srow = t >> 3;            // staging row 0..63
  const int sslot = t & 7;            // global 16B slot 0..7
  const int wslot = (sslot ^ (srow & 7)) * 8;  // swizzled LDS slot (shorts)
  const int rsw = (l16 & 7);          // read-side row parity bits
  short* myPs = &Ps[w][0];

  // Q B-frags (loop-invariant): q-row = q0 + w*16 + l16 (pre-scaled by C1)
  short8 bq0, bq1;
  {
    const short* qsrc = Qh + (q0 + w * 16 + l16) * 64 + quad * 8;
    bq0 = *(const short8*)qsrc;
    bq1 = *(const short8*)(qsrc + 32);
  }

  float m_lane = -1e30f, l_lane = 0.f, xmin_lane = 1e30f;
  f32x4 o_acc[4];
#pragma unroll
  for (int jn = 0; jn < 4; ++jn) o_acc[jn] = {0.f, 0.f, 0.f, 0.f};
  const f32x4 zero = {0.f, 0.f, 0.f, 0.f};

  // swizzled read slot offsets (shorts): kf0 slot = quad^rsw, kf1 = that^4
  const int ksl0 = (quad ^ rsw) * 8;
  const int ksl1 = ((quad ^ rsw) ^ 4) * 8;

  // prefetch tile kt=0 (coalesced; slot = t&7 of the 64-key/64-dh tile)
  short8 pk0 = *(const short8*)(Kh + srow * 64 + sslot * 8);
  short8 pv0 = *(const short8*)(Vh + srow * 2048 + sslot * 8);

  for (int kt = 0; kt < 32; ++kt) {
    __syncthreads();  // prev-iter LDS reads done
    *(short8*)&Ks[srow * 64 + wslot] = pk0;
    *(short8*)&Vts[srow * 64 + wslot] = pv0;
    {  // prefetch next tile; in flight across barrier + compute
      const int ktn = (kt < 31) ? kt + 1 : 31;
      pk0 = *(const short8*)(Kh + (ktn * 64 + srow) * 64 + sslot * 8);
      pv0 = *(const short8*)(Vh + srow * 2048 + ktn * 64 + sslot * 8);
    }
    __syncthreads();  // tiles published

    // S^T = K Q^T: lane holds 16 keys (j*16+quad*4+r) of q-row l16
    f32x4 sacc[4];
#pragma unroll
    for (int j = 0; j < 4; ++j) {
      const int kb = (j * 16 + l16) * 64;
      short8 kf0 = *(const short8*)&Ks[kb + ksl0];
      short8 kf1 = *(const short8*)&Ks[kb + ksl1];
      sacc[j] = MFMA(kf1, bq1, MFMA(kf0, bq0, zero));
    }

    // softmax: x already = s*C1; track max/min/sum, exp2, pack to bf16
    {
      float pmax = m_lane, psum = l_lane, xmn = xmin_lane;
#pragma unroll
      for (int j = 0; j < 4; ++j) {
        const float x0 = sacc[j][0], x1 = sacc[j][1];
        const float x2 = sacc[j][2], x3 = sacc[j][3];
        pmax = fmaxf(fmaxf(x0, fmaxf(x1, x2)), fmaxf(x3, pmax));
        xmn = fminf(fminf(x0, fminf(x1, x2)), fminf(x3, xmn));
        const float e0 = exp2_fast(x0), e1 = exp2_fast(x1);
        const float e2 = exp2_fast(x2), e3 = exp2_fast(x3);
        psum += (e0 + e1) + (e2 + e3);
        union { unsigned int u[2]; short4v s; } pk;
        pk.u[0] = cvtpk(e0, e1);
        pk.u[1] = cvtpk(e2, e3);
        // swizzled write: key-range (16j+4q..+3) at row l16
        *(short4v*)&myPs[l16 * 64 + ((j * 16 + quad * 4) ^ (rsw << 3))] = pk.s;
      }
      m_lane = pmax;
      l_lane = psum;
      xmin_lane = xmn;
    }
    asm volatile("" ::: "memory");  // same-wave DS pipe in-order

    // O' += P V (unnormalized); swizzled 16B-slot reads
#pragma unroll
    for (int tstep = 0; tstep < 2; ++tstep) {
      const int psl = (tstep * 32 + quad * 8) ^ (rsw << 3);
      short8 ap = *(const short8*)&myPs[l16 * 64 + psl];
#pragma unroll
      for (int jn = 0; jn < 4; ++jn) {
        short8 vf = *(const short8*)&Vts[(jn * 16 + l16) * 64 + psl];
        o_acc[jn] = MFMA(ap, vf, o_acc[jn]);
      }
    }
    asm volatile("" ::: "memory");  // Ps reads done before next iter's writes
  }

  // cross-quad reductions (row r lives at lanes l16=r, all quads)
  float l = l_lane;
  l += __shfl_xor(l, 16, 64);
  l += __shfl_xor(l, 32, 64);
  float m = m_lane;
  m = fmaxf(m, __shfl_xor(m, 16, 64));
  m = fmaxf(m, __shfl_xor(m, 32, 64));
  float xm = xmin_lane;
  xm = fminf(xm, __shfl_xor(xm, 16, 64));
  xm = fminf(xm, __shfl_xor(xm, 32, 64));
  float aw = exp2_fast(m) / l;
  float qkx = fmaxf(m, -xm);  // in x-units; /C1 at the very end

  // write O = O'/l (FP32) to [B,S,H*DH]
  const int bidx = bh >> 4, h = bh & 15;
  float linv[4];
#pragma unroll
  for (int r = 0; r < 4; ++r)
    linv[r] = 1.0f / __shfl(l, quad * 4 + r, 16);
#pragma unroll
  for (int jn = 0; jn < 4; ++jn) {
    const int d = jn * 16 + l16;
#pragma unroll
    for (int r = 0; r < 4; ++r) {
      const int s_row = q0 + w * 16 + quad * 4 + r;
      O[((size_t)(bidx * 2048 + s_row) * 1024) + h * 64 + d] =
          o_acc[jn][r] * linv[r];
    }
  }

#pragma unroll
  for (int off = 32; off > 0; off >>= 1) {
    qkx = fmaxf(qkx, __shfl_xor(qkx, off, 64));
    aw = fmaxf(aw, __shfl_xor(aw, off, 64));
  }
  if (lane == 0) {
    redA[w] = qkx;
    redB[w] = aw;
  }
  __syncthreads();
  if (t == 0) {
    float a = redA[0], b = redB[0];
#pragma unroll
    for (int i = 1; i < 8; ++i) {
      a = fmaxf(a, redA[i]);
      b = fmaxf(b, redB[i]);
    }
    atomic_max_f32(&stats[3], a * INV_C1);
    atomic_max_f32(&stats[4], b);
  }
}

// ---------------- finalize 6 scalar outputs (FP32) ----------------
// order: q_max, kT_max, qk_out_max, aw_max, v_max, v_out_max(=aw_max)
__global__ void k_fin(const float* __restrict__ stats, float* __restrict__ out) {
  const int i = threadIdx.x;
  if (i == 0) out[0] = stats[0];
  if (i == 1) out[1] = stats[1];
  if (i == 2) out[2] = stats[3];
  if (i == 3) out[3] = stats[4];
  if (i == 4) out[4] = stats[2];
  if (i == 5) out[5] = stats[4];
}

extern "C" void kernel_launch(void* const* d_in, const int* in_sizes, int n_in,
                              void* d_out, int out_size, void* d_ws, size_t ws_size,
                              hipStream_t stream) {
  const float* X = (const float*)d_in[0];
  const float* Wq = (const float*)d_in[1];
  const float* bq = (const float*)d_in[2];
  const float* Wk = (const float*)d_in[3];
  const float* bk = (const float*)d_in[4];
  const float* Wv = (const float*)d_in[5];
  const float* bv = (const float*)d_in[6];
  float* out = (float*)d_out;

  float* stats = (float*)d_ws;  // 8 floats; poison = atomicMax identity
  short* base = (short*)((char*)d_ws + 4096);
  short* Qb = base;                  // 4096*1024
  short* Kb = base + 4194304;        // 4096*1024
  short* Vb = base + 8388608;        // 4096*1024
  short* Xb = base + 12582912;       // 4096*1024
  short* Wb = base + 16777216;       // 3 * 1024*1024

  k_cvt<<<dim3(2048, 4), 256, 0, stream>>>(X, Wq, Wk, Wv, Xb, Wb);
  k_qkv<<<dim3(8, 32, 3), 256, 0, stream>>>(Xb, Wb, bq, bk, bv, Qb, Kb, Vb, stats);
  k_attn<<<dim3(16, 32), 512, 0, stream>>>(Qb, Kb, Vb, out, stats);
  k_fin<<<1, 64, 0, stream>>>(stats, out + 4194304);
}

// Round 8
// 194.839 us; speedup vs baseline: 1.3686x; 1.0494x over previous
//
#include <hip/hip_runtime.h>
#include <hip/hip_bf16.h>
#include <stdint.h>

typedef __attribute__((ext_vector_type(8))) short short8;
typedef __attribute__((ext_vector_type(4))) short short4v;
typedef __attribute__((ext_vector_type(4))) float f32x4;

#define MFMA(a, b, c) __builtin_amdgcn_mfma_f32_16x16x32_bf16((a), (b), (c), 0, 0, 0)

#define C1 0.18033688011112042f      // 0.125 * log2(e)
#define INV_C1 5.545177444479562f    // 1 / C1

// packed fp32x2 -> bf16x2 (RNE)
static __device__ __forceinline__ unsigned int f2bf2(float x, float y) {
  union { __hip_bfloat162 h; unsigned int u; } c;
  c.h = __float22bfloat162_rn(make_float2(x, y));
  return c.u;
}

// single-instruction HW paths (libm/header versions expand to 6-11 instrs)
static __device__ __forceinline__ float exp2_fast(float x) {
  float r;
  asm("v_exp_f32 %0, %1" : "=v"(r) : "v"(x));
  return r;
}
static __device__ __forceinline__ unsigned int cvtpk(float lo, float hi) {
  unsigned int r;  // dst.lo = bf16(lo), dst.hi = bf16(hi), RNE
  asm("v_cvt_pk_bf16_f32 %0, %1, %2" : "=v"(r) : "v"(lo), "v"(hi));
  return r;
}

// int-ordered max on non-negative floats; ws poison (negative int) = identity
static __device__ __forceinline__ void atomic_max_f32(float* addr, float v) {
  atomicMax((int*)addr, __float_as_int(v));
}

// async global->LDS DMA, 16B per lane; LDS dest is wave-uniform base + lane*16
static __device__ __forceinline__ void gl_lds16(const void* g, void* l) {
  __builtin_amdgcn_global_load_lds(
      (const __attribute__((address_space(1))) void*)g,
      (__attribute__((address_space(3))) void*)l, 16, 0, 0);
}

// ---------------- one-shot fp32 -> bf16 conversion of X, Wq, Wk, Wv --------
__global__ __launch_bounds__(256) void k_cvt(
    const float* __restrict__ X, const float* __restrict__ Wq,
    const float* __restrict__ Wk, const float* __restrict__ Wv,
    short* __restrict__ Xb, short* __restrict__ Wb) {
  const int y = blockIdx.y;
  const float* src;
  short* dst;
  int n;
  if (y == 0) {
    src = X; dst = Xb; n = 4096 * 1024;
  } else {
    src = (y == 1) ? Wq : (y == 2) ? Wk : Wv;
    dst = Wb + (y - 1) * 1048576;
    n = 1048576;
  }
  const int i = (blockIdx.x * 256 + threadIdx.x) * 8;
  if (i >= n) return;
  const float4 a = *(const float4*)(src + i);
  const float4 b = *(const float4*)(src + i + 4);
  union { unsigned int u[4]; short8 s; } P;
  P.u[0] = f2bf2(a.x, a.y);
  P.u[1] = f2bf2(a.z, a.w);
  P.u[2] = f2bf2(b.x, b.y);
  P.u[3] = f2bf2(b.z, b.w);
  *(short8*)(dst + i) = P.s;
}

// ---------------- QKV projection: Y = X @ W^T + b (bf16 inputs) ------------
// 3-BUFFER DEPTH-2 PIPELINE with COUNTED vmcnt (T3+T4): prologue stages
// tiles 0,1; iteration k stages tile k+2, computes tile k, then
//   s_waitcnt lgkmcnt(0) vmcnt(4); s_barrier     (single asm, "memory")
// vmcnt(4) leaves the newest 4 global_load_lds in flight -> each tile's
// loads get TWO compute phases (~600+cyc) to cover L2/HBM latency (the
// __syncthreads version force-drained vmcnt(0) after one phase; measured
// all-pipes-idle at 72us). lgkmcnt(0) guarantees all ds_reads serviced
// before any wave's DMA overwrites that buffer. 10x3 triple-unrolled
// rotation keeps buffer choice + k-offsets compile-time constant.
// CHUNK-MAJOR tiles [4 k-chunk][128 row][16B]: frag read bank = 4*row mod 32
// -> conflict-free (measured 0). DMA dest linear; chunk interleave via
// per-lane GLOBAL source address (m173 pattern).
// Q/K: acc=MFMA(W,X) -> packed [bh][s][dh] stores; V: acc=MFMA(X,W) ->
// packed [bh][dh][s] stores. Q pre-scaled by C1. XCD-chunked swizzle 768=8*96.
__global__ __launch_bounds__(256) void k_qkv(
    const short* __restrict__ Xb, const short* __restrict__ Wball,
    const float* __restrict__ bq, const float* __restrict__ bk,
    const float* __restrict__ bv,
    short* __restrict__ Qo, short* __restrict__ Ko, short* __restrict__ Vo,
    float* __restrict__ stats) {
  const int fid = (blockIdx.z * 32 + blockIdx.y) * 8 + blockIdx.x;
  const int sid = (fid & 7) * 96 + (fid >> 3);
  const int colb = sid & 7;   // N-tile 0..7
  const int zy = sid >> 3;    // 0..95
  const int z = zy >> 5;      // 0..2 (Q/K/V)
  const int yb = zy & 31;     // M-tile 0..31

  const short* W = Wball + z * 1048576;
  const float* bias = (z == 0) ? bq : (z == 1) ? bk : bv;
  short* out = (z == 0) ? Qo : (z == 1) ? Ko : Vo;
  const bool qk = (z < 2);

  __shared__ __align__(16) short B0s[8192];  // A=[0,4096) B=[4096,8192)
  __shared__ __align__(16) short B1s[8192];
  __shared__ __align__(16) short B2s[8192];
  __shared__ float red[4];

  const int t = threadIdx.x;
  const int lane = t & 63;
  const int w = t >> 6;
  const int l16 = lane & 15, quad = lane >> 4;
  const int wr = (w >> 1) * 64, wc = (w & 1) * 64;
  const int row0 = yb * 128;
  const int col0 = colb * 128;

  // DMA: wave w covers chunk-pairs p=w and p=4+w; row=(w&1)*64+lane,
  // global k-offset = (w>>1)*8 + c*16 shorts; LDS shorts [p*512,+512).
  const short* ag = Xb + (size_t)(row0 + (w & 1) * 64 + lane) * 1024 + (w >> 1) * 8;
  const short* bg = W + (size_t)(col0 + (w & 1) * 64 + lane) * 1024 + (w >> 1) * 8;

  // frag bases (z-dependent operand swap): {matbase, rowbase}
  const int f0b = qk ? 4096 : 0, f0r = qk ? wc : wr;
  const int f1b = qk ? 0 : 4096, f1r = qk ? wr : wc;
  const int cq = quad * 1024;  // chunk offset in shorts

  f32x4 acc[4][4];
#pragma unroll
  for (int i = 0; i < 4; ++i)
#pragma unroll
    for (int j = 0; j < 4; ++j) acc[i][j] = {0.f, 0.f, 0.f, 0.f};

#define STAGE(buf, ks_)                                      \
  do {                                                       \
    gl_lds16(ag + (ks_), (buf) + w * 512);                   \
    gl_lds16(ag + (ks_) + 16, (buf) + (4 + w) * 512);        \
    gl_lds16(bg + (ks_), (buf) + 4096 + w * 512);            \
    gl_lds16(bg + (ks_) + 16, (buf) + 4096 + (4 + w) * 512); \
  } while (0)

#define COMPUTE(buf)                                                   \
  do {                                                                 \
    short8 fr0[4], fr1[4];                                             \
    _Pragma("unroll") for (int a = 0; a < 4; ++a)                      \
        fr0[a] = *(const short8*)&(buf)[f0b + cq + (f0r + a * 16 + l16) * 8]; \
    _Pragma("unroll") for (int b = 0; b < 4; ++b)                      \
        fr1[b] = *(const short8*)&(buf)[f1b + cq + (f1r + b * 16 + l16) * 8]; \
    _Pragma("unroll") for (int a = 0; a < 4; ++a)                      \
        _Pragma("unroll") for (int b = 0; b < 4; ++b)                  \
            acc[a][b] = MFMA(fr0[a], fr1[b], acc[a][b]);               \
  } while (0)

// counted barrier: all ds_reads serviced + all but newest N gl_lds landed
#define WAITBAR(n)                                                          \
  do {                                                                      \
    asm volatile("s_waitcnt lgkmcnt(0) vmcnt(" #n ")\n\ts_barrier" ::: "memory"); \
    __builtin_amdgcn_sched_barrier(0);                                      \
  } while (0)

  STAGE(B0s, 0);
  STAGE(B1s, 32);
  WAITBAR(4);  // tile 0 ready; tile 1's 4 loads in flight
  int ks = 64;  // k-offset (shorts) of next tile to stage (tile 2)
#pragma unroll
  for (int i = 0; i < 10; ++i) {  // tiles 0..29; stages tiles 2..31
    STAGE(B2s, ks); ks += 32; COMPUTE(B0s); WAITBAR(4);
    STAGE(B0s, ks); ks += 32; COMPUTE(B1s); WAITBAR(4);
    STAGE(B1s, ks); ks += 32; COMPUTE(B2s); WAITBAR(4);
  }
  COMPUTE(B0s);  // tile 30 (ready: last WAITBAR(4) left only tile 31 in flight)
  WAITBAR(0);    // drain tile 31
  COMPUTE(B1s);  // tile 31
#undef STAGE
#undef COMPUTE
#undef WAITBAR

  const float qs = (z == 0) ? C1 : 1.0f;
  float amax = 0.f;
  if (qk) {
    // acc[a=d-tile][b=s-tile]; C/D: row(quad*4+r)=d, col(l16)=s
#pragma unroll
    for (int a = 0; a < 4; ++a) {
      const int dg = col0 + wc + a * 16 + quad * 4;
      const float4 b4 = *(const float4*)&bias[dg];
      const int h = dg >> 6, dl = dg & 63;
#pragma unroll
      for (int b = 0; b < 4; ++b) {
        const int sg = row0 + wr + b * 16 + l16;
        const float y0 = acc[a][b][0] + b4.x;
        const float y1 = acc[a][b][1] + b4.y;
        const float y2 = acc[a][b][2] + b4.z;
        const float y3 = acc[a][b][3] + b4.w;
        amax = fmaxf(amax, fmaxf(fmaxf(fabsf(y0), fabsf(y1)), fmaxf(fabsf(y2), fabsf(y3))));
        union { unsigned int u[2]; short4v s; } pk;
        pk.u[0] = cvtpk(y0 * qs, y1 * qs);
        pk.u[1] = cvtpk(y2 * qs, y3 * qs);
        const int bidx = sg >> 11, sl = sg & 2047;
        *(short4v*)&out[(size_t)(((bidx << 4) | h) * 2048 + sl) * 64 + dl] = pk.s;
      }
    }
  } else {
    // acc[a=s-tile][b=d-tile]; C/D: row(quad*4+r)=s, col(l16)=d
#pragma unroll
    for (int a = 0; a < 4; ++a) {
      const int sg = row0 + wr + a * 16 + quad * 4;
      const int bidx = sg >> 11, sl = sg & 2047;
#pragma unroll
      for (int b = 0; b < 4; ++b) {
        const int dg = col0 + wc + b * 16 + l16;
        const float bvf = bias[dg];
        const int h = dg >> 6, dl = dg & 63;
        const float y0 = acc[a][b][0] + bvf;
        const float y1 = acc[a][b][1] + bvf;
        const float y2 = acc[a][b][2] + bvf;
        const float y3 = acc[a][b][3] + bvf;
        amax = fmaxf(amax, fmaxf(fmaxf(fabsf(y0), fabsf(y1)), fmaxf(fabsf(y2), fabsf(y3))));
        union { unsigned int u[2]; short4v s; } pk;
        pk.u[0] = cvtpk(y0, y1);
        pk.u[1] = cvtpk(y2, y3);
        *(short4v*)&out[(size_t)(((bidx << 4) | h) * 64 + dl) * 2048 + sl] = pk.s;
      }
    }
  }
#pragma unroll
  for (int off = 32; off > 0; off >>= 1)
    amax = fmaxf(amax, __shfl_xor(amax, off, 64));
  if (lane == 0) red[w] = amax;
  __syncthreads();
  if (t == 0) {
    float m = fmaxf(fmaxf(red[0], red[1]), fmaxf(red[2], red[3]));
    atomic_max_f32(&stats[z], m);  // 0=q,1=k,2=v
  }
}

// ---------------- flash attention: 8 waves x 16 q-rows + T2 XOR swizzle ----
// (unchanged from round 6 -- attribution; exp2_fast/cvtpk VALU cut landed)
// grid (16,32)=512 blocks; block 512 = 8 waves; wave owns 16 q-rows.
// Q pre-scaled by C1 -> sacc IS the exp2 arg; no-rescale softmax with
// per-lane (max,min,sum); qk_out_max = max(m,-xmin)/C1; O = O'/l at end.
// XCD swizzle 512 = 8*64: XCD k owns heads 4k..4k+3 (K/V L2-resident).
__global__ __launch_bounds__(512) void k_attn(
    const short* __restrict__ Q, const short* __restrict__ K,
    const short* __restrict__ V, float* __restrict__ O,
    float* __restrict__ stats) {
  const int fid = blockIdx.y * 16 + blockIdx.x;
  const int sid = ((fid & 7) << 6) + (fid >> 3);  // bijective: 512 = 8*64
  const int bh = sid >> 4;
  const int q0 = (sid & 15) << 7;
  const short* Qh = Q + (size_t)bh * 2048 * 64;
  const short* Kh = K + (size_t)bh * 2048 * 64;
  const short* Vh = V + (size_t)bh * 2048 * 64;  // [dh=64][s=2048]

  __shared__ __align__(16) short Ks[64 * 64];   // [key][dh] swizzled
  __shared__ __align__(16) short Vts[64 * 64];  // [dh][key] swizzled
  __shared__ __align__(16) short Ps[8][16 * 64];  // swizzled
  __shared__ float redA[8], redB[8];

  const int t = threadIdx.x, lane = t & 63, w = t >> 6;  // w 0..7
  const int l16 = lane & 15, quad = lane >> 4;
  const int srow = t >> 3;            // staging row 0..63
  const int sslot = t & 7;            // global 16B slot 0..7
  const int wslot = (sslot ^ (srow & 7)) * 8;  // swizzled LDS slot (shorts)
  const int rsw = (l16 & 7);          // read-side row parity bits
  short* myPs = &Ps[w][0];

  // Q B-frags (loop-invariant): q-row = q0 + w*16 + l16 (pre-scaled by C1)
  short8 bq0, bq1;
  {
    const short* qsrc = Qh + (q0 + w * 16 + l16) * 64 + quad * 8;
    bq0 = *(const short8*)qsrc;
    bq1 = *(const short8*)(qsrc + 32);
  }

  float m_lane = -1e30f, l_lane = 0.f, xmin_lane = 1e30f;
  f32x4 o_acc[4];
#pragma unroll
  for (int jn = 0; jn < 4; ++jn) o_acc[jn] = {0.f, 0.f, 0.f, 0.f};
  const f32x4 zero = {0.f, 0.f, 0.f, 0.f};

  // swizzled read slot offsets (shorts): kf0 slot = quad^rsw, kf1 = that^4
  const int ksl0 = (quad ^ rsw) * 8;
  const int ksl1 = ((quad ^ rsw) ^ 4) * 8;

  // prefetch tile kt=0 (coalesced; slot = t&7 of the 64-key/64-dh tile)
  short8 pk0 = *(const short8*)(Kh + srow * 64 + sslot * 8);
  short8 pv0 = *(const short8*)(Vh + srow * 2048 + sslot * 8);

  for (int kt = 0; kt < 32; ++kt) {
    __syncthreads();  // prev-iter LDS reads done
    *(short8*)&Ks[srow * 64 + wslot] = pk0;
    *(short8*)&Vts[srow * 64 + wslot] = pv0;
    {  // prefetch next tile; in flight across barrier + compute
      const int ktn = (kt < 31) ? kt + 1 : 31;
      pk0 = *(const short8*)(Kh + (ktn * 64 + srow) * 64 + sslot * 8);
      pv0 = *(const short8*)(Vh + srow * 2048 + ktn * 64 + sslot * 8);
    }
    __syncthreads();  // tiles published

    // S^T = K Q^T: lane holds 16 keys (j*16+quad*4+r) of q-row l16
    f32x4 sacc[4];
#pragma unroll
    for (int j = 0; j < 4; ++j) {
      const int kb = (j * 16 + l16) * 64;
      short8 kf0 = *(const short8*)&Ks[kb + ksl0];
      short8 kf1 = *(const short8*)&Ks[kb + ksl1];
      sacc[j] = MFMA(kf1, bq1, MFMA(kf0, bq0, zero));
    }

    // softmax: x already = s*C1; track max/min/sum, exp2, pack to bf16
    {
      float pmax = m_lane, psum = l_lane, xmn = xmin_lane;
#pragma unroll
      for (int j = 0; j < 4; ++j) {
        const float x0 = sacc[j][0], x1 = sacc[j][1];
        const float x2 = sacc[j][2], x3 = sacc[j][3];
        pmax = fmaxf(fmaxf(x0, fmaxf(x1, x2)), fmaxf(x3, pmax));
        xmn = fminf(fminf(x0, fminf(x1, x2)), fminf(x3, xmn));
        const float e0 = exp2_fast(x0), e1 = exp2_fast(x1);
        const float e2 = exp2_fast(x2), e3 = exp2_fast(x3);
        psum += (e0 + e1) + (e2 + e3);
        union { unsigned int u[2]; short4v s; } pk;
        pk.u[0] = cvtpk(e0, e1);
        pk.u[1] = cvtpk(e2, e3);
        // swizzled write: key-range (16j+4q..+3) at row l16
        *(short4v*)&myPs[l16 * 64 + ((j * 16 + quad * 4) ^ (rsw << 3))] = pk.s;
      }
      m_lane = pmax;
      l_lane = psum;
      xmin_lane = xmn;
    }
    asm volatile("" ::: "memory");  // same-wave DS pipe in-order

    // O' += P V (unnormalized); swizzled 16B-slot reads
#pragma unroll
    for (int tstep = 0; tstep < 2; ++tstep) {
      const int psl = (tstep * 32 + quad * 8) ^ (rsw << 3);
      short8 ap = *(const short8*)&myPs[l16 * 64 + psl];
#pragma unroll
      for (int jn = 0; jn < 4; ++jn) {
        short8 vf = *(const short8*)&Vts[(jn * 16 + l16) * 64 + psl];
        o_acc[jn] = MFMA(ap, vf, o_acc[jn]);
      }
    }
    asm volatile("" ::: "memory");  // Ps reads done before next iter's writes
  }

  // cross-quad reductions (row r lives at lanes l16=r, all quads)
  float l = l_lane;
  l += __shfl_xor(l, 16, 64);
  l += __shfl_xor(l, 32, 64);
  float m = m_lane;
  m = fmaxf(m, __shfl_xor(m, 16, 64));
  m = fmaxf(m, __shfl_xor(m, 32, 64));
  float xm = xmin_lane;
  xm = fminf(xm, __shfl_xor(xm, 16, 64));
  xm = fminf(xm, __shfl_xor(xm, 32, 64));
  float aw = exp2_fast(m) / l;
  float qkx = fmaxf(m, -xm);  // in x-units; /C1 at the very end

  // write O = O'/l (FP32) to [B,S,H*DH]
  const int bidx = bh >> 4, h = bh & 15;
  float linv[4];
#pragma unroll
  for (int r = 0; r < 4; ++r)
    linv[r] = 1.0f / __shfl(l, quad * 4 + r, 16);
#pragma unroll
  for (int jn = 0; jn < 4; ++jn) {
    const int d = jn * 16 + l16;
#pragma unroll
    for (int r = 0; r < 4; ++r) {
      const int s_row = q0 + w * 16 + quad * 4 + r;
      O[((size_t)(bidx * 2048 + s_row) * 1024) + h * 64 + d] =
          o_acc[jn][r] * linv[r];
    }
  }

#pragma unroll
  for (int off = 32; off > 0; off >>= 1) {
    qkx = fmaxf(qkx, __shfl_xor(qkx, off, 64));
    aw = fmaxf(aw, __shfl_xor(aw, off, 64));
  }
  if (lane == 0) {
    redA[w] = qkx;
    redB[w] = aw;
  }
  __syncthreads();
  if (t == 0) {
    float a = redA[0], b = redB[0];
#pragma unroll
    for (int i = 1; i < 8; ++i) {
      a = fmaxf(a, redA[i]);
      b = fmaxf(b, redB[i]);
    }
    atomic_max_f32(&stats[3], a * INV_C1);
    atomic_max_f32(&stats[4], b);
  }
}

// ---------------- finalize 6 scalar outputs (FP32) ----------------
// order: q_max, kT_max, qk_out_max, aw_max, v_max, v_out_max(=aw_max)
__global__ void k_fin(const float* __restrict__ stats, float* __restrict__ out) {
  const int i = threadIdx.x;
  if (i == 0) out[0] = stats[0];
  if (i == 1) out[1] = stats[1];
  if (i == 2) out[2] = stats[3];
  if (i == 3) out[3] = stats[4];
  if (i == 4) out[4] = stats[2];
  if (i == 5) out[5] = stats[4];
}

extern "C" void kernel_launch(void* const* d_in, const int* in_sizes, int n_in,
                              void* d_out, int out_size, void* d_ws, size_t ws_size,
                              hipStream_t stream) {
  const float* X = (const float*)d_in[0];
  const float* Wq = (const float*)d_in[1];
  const float* bq = (const float*)d_in[2];
  const float* Wk = (const float*)d_in[3];
  const float* bk = (const float*)d_in[4];
  const float* Wv = (const float*)d_in[5];
  const float* bv = (const float*)d_in[6];
  float* out = (float*)d_out;

  float* stats = (float*)d_ws;  // 8 floats; poison = atomicMax identity
  short* base = (short*)((char*)d_ws + 4096);
  short* Qb = base;                  // 4096*1024
  short* Kb = base + 4194304;        // 4096*1024
  short* Vb = base + 8388608;        // 4096*1024
  short* Xb = base + 12582912;       // 4096*1024
  short* Wb = base + 16777216;       // 3 * 1024*1024

  k_cvt<<<dim3(2048, 4), 256, 0, stream>>>(X, Wq, Wk, Wv, Xb, Wb);
  k_qkv<<<dim3(8, 32, 3), 256, 0, stream>>>(Xb, Wb, bq, bk, bv, Qb, Kb, Vb, stats);
  k_attn<<<dim3(16, 32), 512, 0, stream>>>(Qb, Kb, Vb, out, stats);
  k_fin<<<1, 64, 0, stream>>>(stats, out + 4194304);
}

// Round 9
// 181.129 us; speedup vs baseline: 1.4721x; 1.0757x over previous
//
#include <hip/hip_runtime.h>
#include <hip/hip_bf16.h>
#include <stdint.h>

typedef __attribute__((ext_vector_type(8))) short short8;
typedef __attribute__((ext_vector_type(4))) short short4v;
typedef __attribute__((ext_vector_type(4))) float f32x4;

#define MFMA(a, b, c) __builtin_amdgcn_mfma_f32_16x16x32_bf16((a), (b), (c), 0, 0, 0)

#define C1 0.18033688011112042f      // 0.125 * log2(e)
#define INV_C1 5.545177444479562f    // 1 / C1

// packed fp32x2 -> bf16x2 (RNE)
static __device__ __forceinline__ unsigned int f2bf2(float x, float y) {
  union { __hip_bfloat162 h; unsigned int u; } c;
  c.h = __float22bfloat162_rn(make_float2(x, y));
  return c.u;
}

// single-instruction HW paths (libm/header versions expand to 6-11 instrs)
static __device__ __forceinline__ float exp2_fast(float x) {
  float r;
  asm("v_exp_f32 %0, %1" : "=v"(r) : "v"(x));
  return r;
}
static __device__ __forceinline__ unsigned int cvtpk(float lo, float hi) {
  unsigned int r;  // dst.lo = bf16(lo), dst.hi = bf16(hi), RNE
  asm("v_cvt_pk_bf16_f32 %0, %1, %2" : "=v"(r) : "v"(lo), "v"(hi));
  return r;
}

// int-ordered max on non-negative floats; ws poison (negative int) = identity
static __device__ __forceinline__ void atomic_max_f32(float* addr, float v) {
  atomicMax((int*)addr, __float_as_int(v));
}

// async global->LDS DMA, 16B per lane; LDS dest is wave-uniform base + lane*16
static __device__ __forceinline__ void gl_lds16(const void* g, void* l) {
  __builtin_amdgcn_global_load_lds(
      (const __attribute__((address_space(1))) void*)g,
      (__attribute__((address_space(3))) void*)l, 16, 0, 0);
}

// ---------------- fp32 -> bf16 conversion INTO PRE-TILED layouts ----------
// Xb: [yb 0..31][kk 0..31][q 0..3][r 0..127][j 0..7]  (4096-short tiles,
//     tile = LDS staging image for k_qkv: contiguous 8KB per (yb,kk))
// Wb: [z][colb 0..7][kk][q][r][j]  (same image per (z,colb,kk))
// element (row s, col c): yb=s>>7, r=s&127, kk=c>>5, q=(c>>3)&3, j=c&7
// -> off = ((blk*32+kk)*4+q)*1024 + r*8 + j.
// Reads stay fully coalesced (8 consecutive fp32/thread); writes are 16B
// scattered (stride 2KB) -- k_cvt is BW-bound + massively parallel, cheap.
// This makes k_qkv's gl_lds16 CONTIGUOUS (16 lines/instr vs 64 = the
// VMEM-transaction bottleneck measured in round 8).
__global__ __launch_bounds__(256) void k_cvt(
    const float* __restrict__ X, const float* __restrict__ Wq,
    const float* __restrict__ Wk, const float* __restrict__ Wv,
    short* __restrict__ Xb, short* __restrict__ Wb) {
  const int y = blockIdx.y;
  const int i = (blockIdx.x * 256 + threadIdx.x) * 8;
  const float* src;
  short* dstbase;
  if (y == 0) {
    if (i >= 4096 * 1024) return;
    src = X;
    dstbase = Xb;
  } else {
    if (i >= 1048576) return;
    src = (y == 1) ? Wq : (y == 2) ? Wk : Wv;
    dstbase = Wb + (y - 1) * 1048576;
  }
  const float4 a = *(const float4*)(src + i);
  const float4 b = *(const float4*)(src + i + 4);
  union { unsigned int u[4]; short8 s; } P;
  P.u[0] = f2bf2(a.x, a.y);
  P.u[1] = f2bf2(a.z, a.w);
  P.u[2] = f2bf2(b.x, b.y);
  P.u[3] = f2bf2(b.z, b.w);
  const int s = i >> 10, c0 = i & 1023;  // source row, col
  const int off = (((s >> 7) * 32 + (c0 >> 5)) * 4 + ((c0 >> 3) & 3)) * 1024 +
                  (s & 127) * 8;
  *(short8*)(dstbase + off) = P.s;
}

// ---------------- QKV projection: Y = X @ W^T + b (bf16 inputs) ------------
// 3-BUFFER DEPTH-2 PIPELINE with COUNTED vmcnt (T3+T4), unchanged from r8:
//   s_waitcnt lgkmcnt(0) vmcnt(4); s_barrier   per tile (never 0 in loop).
// NEW: staging sources are PRE-TILED (k_cvt): each (yb,kk)/(z,colb,kk) tile
// is a contiguous 8KB block in the exact LDS image [q][r][8]. Each gl_lds16
// reads contiguous 1KB (lane*16B) -> 16 cache lines/instr, 4 lanes/line
// (was 64 lines/instr with 2KB/lane stride = the measured r8 bottleneck:
// ~3072 line-transactions/CU-kstep ~ the 4936-cyc wall).
// Frag reads unchanged: chunk-major image, bank = 4*row mod 32, 0 conflicts.
// Q/K: acc=MFMA(W,X) -> packed [bh][s][dh] stores; V: acc=MFMA(X,W) ->
// packed [bh][dh][s] stores. Q pre-scaled by C1. XCD-chunked swizzle 768=8*96.
__global__ __launch_bounds__(256) void k_qkv(
    const short* __restrict__ Xb, const short* __restrict__ Wball,
    const float* __restrict__ bq, const float* __restrict__ bk,
    const float* __restrict__ bv,
    short* __restrict__ Qo, short* __restrict__ Ko, short* __restrict__ Vo,
    float* __restrict__ stats) {
  const int fid = (blockIdx.z * 32 + blockIdx.y) * 8 + blockIdx.x;
  const int sid = (fid & 7) * 96 + (fid >> 3);
  const int colb = sid & 7;   // N-tile 0..7
  const int zy = sid >> 3;    // 0..95
  const int z = zy >> 5;      // 0..2 (Q/K/V)
  const int yb = zy & 31;     // M-tile 0..31

  const float* bias = (z == 0) ? bq : (z == 1) ? bk : bv;
  short* out = (z == 0) ? Qo : (z == 1) ? Ko : Vo;
  const bool qk = (z < 2);

  __shared__ __align__(16) short B0s[8192];  // A=[0,4096) B=[4096,8192)
  __shared__ __align__(16) short B1s[8192];
  __shared__ __align__(16) short B2s[8192];
  __shared__ float red[4];

  const int t = threadIdx.x;
  const int lane = t & 63;
  const int w = t >> 6;
  const int l16 = lane & 15, quad = lane >> 4;
  const int wr = (w >> 1) * 64, wc = (w & 1) * 64;
  const int row0 = yb * 128;
  const int col0 = colb * 128;

  // pre-tiled staging bases: tile(kk) = base + kk*4096 shorts (contiguous)
  const short* ag = Xb + yb * 131072 + w * 512 + lane * 8;
  const short* bg = Wball + z * 1048576 + colb * 131072 + w * 512 + lane * 8;

  // frag bases (z-dependent operand swap): {matbase, rowbase}
  const int f0b = qk ? 4096 : 0, f0r = qk ? wc : wr;
  const int f1b = qk ? 0 : 4096, f1r = qk ? wr : wc;
  const int cq = quad * 1024;  // chunk offset in shorts

  f32x4 acc[4][4];
#pragma unroll
  for (int i = 0; i < 4; ++i)
#pragma unroll
    for (int j = 0; j < 4; ++j) acc[i][j] = {0.f, 0.f, 0.f, 0.f};

#define STAGE(buf, ko_)                                  \
  do {                                                   \
    gl_lds16(ag + (ko_), (buf) + w * 512);               \
    gl_lds16(ag + (ko_) + 2048, (buf) + 2048 + w * 512); \
    gl_lds16(bg + (ko_), (buf) + 4096 + w * 512);        \
    gl_lds16(bg + (ko_) + 2048, (buf) + 6144 + w * 512); \
  } while (0)

#define COMPUTE(buf)                                                   \
  do {                                                                 \
    short8 fr0[4], fr1[4];                                             \
    _Pragma("unroll") for (int a = 0; a < 4; ++a)                      \
        fr0[a] = *(const short8*)&(buf)[f0b + cq + (f0r + a * 16 + l16) * 8]; \
    _Pragma("unroll") for (int b = 0; b < 4; ++b)                      \
        fr1[b] = *(const short8*)&(buf)[f1b + cq + (f1r + b * 16 + l16) * 8]; \
    _Pragma("unroll") for (int a = 0; a < 4; ++a)                      \
        _Pragma("unroll") for (int b = 0; b < 4; ++b)                  \
            acc[a][b] = MFMA(fr0[a], fr1[b], acc[a][b]);               \
  } while (0)

// counted barrier: all ds_reads serviced + all but newest N gl_lds landed
#define WAITBAR(n)                                                          \
  do {                                                                      \
    asm volatile("s_waitcnt lgkmcnt(0) vmcnt(" #n ")\n\ts_barrier" ::: "memory"); \
    __builtin_amdgcn_sched_barrier(0);                                      \
  } while (0)

  STAGE(B0s, 0);
  STAGE(B1s, 4096);
  WAITBAR(4);   // tile 0 ready; tile 1's 4 loads in flight
  int ks = 8192;  // short-offset of next tile to stage (tile 2)
#pragma unroll
  for (int i = 0; i < 10; ++i) {  // tiles 0..29; stages tiles 2..31
    STAGE(B2s, ks); ks += 4096; COMPUTE(B0s); WAITBAR(4);
    STAGE(B0s, ks); ks += 4096; COMPUTE(B1s); WAITBAR(4);
    STAGE(B1s, ks); ks += 4096; COMPUTE(B2s); WAITBAR(4);
  }
  COMPUTE(B0s);  // tile 30 (ready: last WAITBAR(4) left only tile 31 in flight)
  WAITBAR(0);    // drain tile 31
  COMPUTE(B1s);  // tile 31
#undef STAGE
#undef COMPUTE
#undef WAITBAR

  const float qs = (z == 0) ? C1 : 1.0f;
  float amax = 0.f;
  if (qk) {
    // acc[a=d-tile][b=s-tile]; C/D: row(quad*4+r)=d, col(l16)=s
#pragma unroll
    for (int a = 0; a < 4; ++a) {
      const int dg = col0 + wc + a * 16 + quad * 4;
      const float4 b4 = *(const float4*)&bias[dg];
      const int h = dg >> 6, dl = dg & 63;
#pragma unroll
      for (int b = 0; b < 4; ++b) {
        const int sg = row0 + wr + b * 16 + l16;
        const float y0 = acc[a][b][0] + b4.x;
        const float y1 = acc[a][b][1] + b4.y;
        const float y2 = acc[a][b][2] + b4.z;
        const float y3 = acc[a][b][3] + b4.w;
        amax = fmaxf(amax, fmaxf(fmaxf(fabsf(y0), fabsf(y1)), fmaxf(fabsf(y2), fabsf(y3))));
        union { unsigned int u[2]; short4v s; } pk;
        pk.u[0] = cvtpk(y0 * qs, y1 * qs);
        pk.u[1] = cvtpk(y2 * qs, y3 * qs);
        const int bidx = sg >> 11, sl = sg & 2047;
        *(short4v*)&out[(size_t)(((bidx << 4) | h) * 2048 + sl) * 64 + dl] = pk.s;
      }
    }
  } else {
    // acc[a=s-tile][b=d-tile]; C/D: row(quad*4+r)=s, col(l16)=d
#pragma unroll
    for (int a = 0; a < 4; ++a) {
      const int sg = row0 + wr + a * 16 + quad * 4;
      const int bidx = sg >> 11, sl = sg & 2047;
#pragma unroll
      for (int b = 0; b < 4; ++b) {
        const int dg = col0 + wc + b * 16 + l16;
        const float bvf = bias[dg];
        const int h = dg >> 6, dl = dg & 63;
        const float y0 = acc[a][b][0] + bvf;
        const float y1 = acc[a][b][1] + bvf;
        const float y2 = acc[a][b][2] + bvf;
        const float y3 = acc[a][b][3] + bvf;
        amax = fmaxf(amax, fmaxf(fmaxf(fabsf(y0), fabsf(y1)), fmaxf(fabsf(y2), fabsf(y3))));
        union { unsigned int u[2]; short4v s; } pk;
        pk.u[0] = cvtpk(y0, y1);
        pk.u[1] = cvtpk(y2, y3);
        *(short4v*)&out[(size_t)(((bidx << 4) | h) * 64 + dl) * 2048 + sl] = pk.s;
      }
    }
  }
#pragma unroll
  for (int off = 32; off > 0; off >>= 1)
    amax = fmaxf(amax, __shfl_xor(amax, off, 64));
  if (lane == 0) red[w] = amax;
  __syncthreads();
  if (t == 0) {
    float m = fmaxf(fmaxf(red[0], red[1]), fmaxf(red[2], red[3]));
    atomic_max_f32(&stats[z], m);  // 0=q,1=k,2=v
  }
}

// ---------------- flash attention: 8 waves x 16 q-rows + T2 XOR swizzle ----
// (unchanged from round 8 -- attribution)
// grid (16,32)=512 blocks; block 512 = 8 waves; wave owns 16 q-rows.
// Q pre-scaled by C1 -> sacc IS the exp2 arg; no-rescale softmax with
// per-lane (max,min,sum); qk_out_max = max(m,-xmin)/C1; O = O'/l at end.
// XCD swizzle 512 = 8*64: XCD k owns heads 4k..4k+3 (K/V L2-resident).
__global__ __launch_bounds__(512) void k_attn(
    const short* __restrict__ Q, const short* __restrict__ K,
    const short* __restrict__ V, float* __restrict__ O,
    float* __restrict__ stats) {
  const int fid = blockIdx.y * 16 + blockIdx.x;
  const int sid = ((fid & 7) << 6) + (fid >> 3);  // bijective: 512 = 8*64
  const int bh = sid >> 4;
  const int q0 = (sid & 15) << 7;
  const short* Qh = Q + (size_t)bh * 2048 * 64;
  const short* Kh = K + (size_t)bh * 2048 * 64;
  const short* Vh = V + (size_t)bh * 2048 * 64;  // [dh=64][s=2048]

  __shared__ __align__(16) short Ks[64 * 64];   // [key][dh] swizzled
  __shared__ __align__(16) short Vts[64 * 64];  // [dh][key] swizzled
  __shared__ __align__(16) short Ps[8][16 * 64];  // swizzled
  __shared__ float redA[8], redB[8];

  const int t = threadIdx.x, lane = t & 63, w = t >> 6;  // w 0..7
  const int l16 = lane & 15, quad = lane >> 4;
  const int srow = t >> 3;            // staging row 0..63
  const int sslot = t & 7;            // global 16B slot 0..7
  const int wslot = (sslot ^ (srow & 7)) * 8;  // swizzled LDS slot (shorts)
  const int rsw = (l16 & 7);          // read-side row parity bits
  short* myPs = &Ps[w][0];

  // Q B-frags (loop-invariant): q-row = q0 + w*16 + l16 (pre-scaled by C1)
  short8 bq0, bq1;
  {
    const short* qsrc = Qh + (q0 + w * 16 + l16) * 64 + quad * 8;
    bq0 = *(const short8*)qsrc;
    bq1 = *(const short8*)(qsrc + 32);
  }

  float m_lane = -1e30f, l_lane = 0.f, xmin_lane = 1e30f;
  f32x4 o_acc[4];
#pragma unroll
  for (int jn = 0; jn < 4; ++jn) o_acc[jn] = {0.f, 0.f, 0.f, 0.f};
  const f32x4 zero = {0.f, 0.f, 0.f, 0.f};

  // swizzled read slot offsets (shorts): kf0 slot = quad^rsw, kf1 = that^4
  const int ksl0 = (quad ^ rsw) * 8;
  const int ksl1 = ((quad ^ rsw) ^ 4) * 8;

  // prefetch tile kt=0 (coalesced; slot = t&7 of the 64-key/64-dh tile)
  short8 pk0 = *(const short8*)(Kh + srow * 64 + sslot * 8);
  short8 pv0 = *(const short8*)(Vh + srow * 2048 + sslot * 8);

  for (int kt = 0; kt < 32; ++kt) {
    __syncthreads();  // prev-iter LDS reads done
    *(short8*)&Ks[srow * 64 + wslot] = pk0;
    *(short8*)&Vts[srow * 64 + wslot] = pv0;
    {  // prefetch next tile; in flight across barrier + compute
      const int ktn = (kt < 31) ? kt + 1 : 31;
      pk0 = *(const short8*)(Kh + (ktn * 64 + srow) * 64 + sslot * 8);
      pv0 = *(const short8*)(Vh + srow * 2048 + ktn * 64 + sslot * 8);
    }
    __syncthreads();  // tiles published

    // S^T = K Q^T: lane holds 16 keys (j*16+quad*4+r) of q-row l16
    f32x4 sacc[4];
#pragma unroll
    for (int j = 0; j < 4; ++j) {
      const int kb = (j * 16 + l16) * 64;
      short8 kf0 = *(const short8*)&Ks[kb + ksl0];
      short8 kf1 = *(const short8*)&Ks[kb + ksl1];
      sacc[j] = MFMA(kf1, bq1, MFMA(kf0, bq0, zero));
    }

    // softmax: x already = s*C1; track max/min/sum, exp2, pack to bf16
    {
      float pmax = m_lane, psum = l_lane, xmn = xmin_lane;
#pragma unroll
      for (int j = 0; j < 4; ++j) {
        const float x0 = sacc[j][0], x1 = sacc[j][1];
        const float x2 = sacc[j][2], x3 = sacc[j][3];
        pmax = fmaxf(fmaxf(x0, fmaxf(x1, x2)), fmaxf(x3, pmax));
        xmn = fminf(fminf(x0, fminf(x1, x2)), fminf(x3, xmn));
        const float e0 = exp2_fast(x0), e1 = exp2_fast(x1);
        const float e2 = exp2_fast(x2), e3 = exp2_fast(x3);
        psum += (e0 + e1) + (e2 + e3);
        union { unsigned int u[2]; short4v s; } pk;
        pk.u[0] = cvtpk(e0, e1);
        pk.u[1] = cvtpk(e2, e3);
        // swizzled write: key-range (16j+4q..+3) at row l16
        *(short4v*)&myPs[l16 * 64 + ((j * 16 + quad * 4) ^ (rsw << 3))] = pk.s;
      }
      m_lane = pmax;
      l_lane = psum;
      xmin_lane = xmn;
    }
    asm volatile("" ::: "memory");  // same-wave DS pipe in-order

    // O' += P V (unnormalized); swizzled 16B-slot reads
#pragma unroll
    for (int tstep = 0; tstep < 2; ++tstep) {
      const int psl = (tstep * 32 + quad * 8) ^ (rsw << 3);
      short8 ap = *(const short8*)&myPs[l16 * 64 + psl];
#pragma unroll
      for (int jn = 0; jn < 4; ++jn) {
        short8 vf = *(const short8*)&Vts[(jn * 16 + l16) * 64 + psl];
        o_acc[jn] = MFMA(ap, vf, o_acc[jn]);
      }
    }
    asm volatile("" ::: "memory");  // Ps reads done before next iter's writes
  }

  // cross-quad reductions (row r lives at lanes l16=r, all quads)
  float l = l_lane;
  l += __shfl_xor(l, 16, 64);
  l += __shfl_xor(l, 32, 64);
  float m = m_lane;
  m = fmaxf(m, __shfl_xor(m, 16, 64));
  m = fmaxf(m, __shfl_xor(m, 32, 64));
  float xm = xmin_lane;
  xm = fminf(xm, __shfl_xor(xm, 16, 64));
  xm = fminf(xm, __shfl_xor(xm, 32, 64));
  float aw = exp2_fast(m) / l;
  float qkx = fmaxf(m, -xm);  // in x-units; /C1 at the very end

  // write O = O'/l (FP32) to [B,S,H*DH]
  const int bidx = bh >> 4, h = bh & 15;
  float linv[4];
#pragma unroll
  for (int r = 0; r < 4; ++r)
    linv[r] = 1.0f / __shfl(l, quad * 4 + r, 16);
#pragma unroll
  for (int jn = 0; jn < 4; ++jn) {
    const int d = jn * 16 + l16;
#pragma unroll
    for (int r = 0; r < 4; ++r) {
      const int s_row = q0 + w * 16 + quad * 4 + r;
      O[((size_t)(bidx * 2048 + s_row) * 1024) + h * 64 + d] =
          o_acc[jn][r] * linv[r];
    }
  }

#pragma unroll
  for (int off = 32; off > 0; off >>= 1) {
    qkx = fmaxf(qkx, __shfl_xor(qkx, off, 64));
    aw = fmaxf(aw, __shfl_xor(aw, off, 64));
  }
  if (lane == 0) {
    redA[w] = qkx;
    redB[w] = aw;
  }
  __syncthreads();
  if (t == 0) {
    float a = redA[0], b = redB[0];
#pragma unroll
    for (int i = 1; i < 8; ++i) {
      a = fmaxf(a, redA[i]);
      b = fmaxf(b, redB[i]);
    }
    atomic_max_f32(&stats[3], a * INV_C1);
    atomic_max_f32(&stats[4], b);
  }
}

// ---------------- finalize 6 scalar outputs (FP32) ----------------
// order: q_max, kT_max, qk_out_max, aw_max, v_max, v_out_max(=aw_max)
__global__ void k_fin(const float* __restrict__ stats, float* __restrict__ out) {
  const int i = threadIdx.x;
  if (i == 0) out[0] = stats[0];
  if (i == 1) out[1] = stats[1];
  if (i == 2) out[2] = stats[3];
  if (i == 3) out[3] = stats[4];
  if (i == 4) out[4] = stats[2];
  if (i == 5) out[5] = stats[4];
}

extern "C" void kernel_launch(void* const* d_in, const int* in_sizes, int n_in,
                              void* d_out, int out_size, void* d_ws, size_t ws_size,
                              hipStream_t stream) {
  const float* X = (const float*)d_in[0];
  const float* Wq = (const float*)d_in[1];
  const float* bq = (const float*)d_in[2];
  const float* Wk = (const float*)d_in[3];
  const float* bk = (const float*)d_in[4];
  const float* Wv = (const float*)d_in[5];
  const float* bv = (const float*)d_in[6];
  float* out = (float*)d_out;

  float* stats = (float*)d_ws;  // 8 floats; poison = atomicMax identity
  short* base = (short*)((char*)d_ws + 4096);
  short* Qb = base;                  // 4096*1024
  short* Kb = base + 4194304;        // 4096*1024
  short* Vb = base + 8388608;        // 4096*1024
  short* Xb = base + 12582912;       // 4096*1024 (pre-tiled)
  short* Wb = base + 16777216;       // 3 * 1024*1024 (pre-tiled)

  k_cvt<<<dim3(2048, 4), 256, 0, stream>>>(X, Wq, Wk, Wv, Xb, Wb);
  k_qkv<<<dim3(8, 32, 3), 256, 0, stream>>>(Xb, Wb, bq, bk, bv, Qb, Kb, Vb, stats);
  k_attn<<<dim3(16, 32), 512, 0, stream>>>(Qb, Kb, Vb, out, stats);
  k_fin<<<1, 64, 0, stream>>>(stats, out + 4194304);
}